// Round 1
// baseline (914.953 us; speedup 1.0000x reference)
//
#include <hip/hip_runtime.h>
#include <cstdint>
#include <cstddef>

#define NNODES 50000
#define NEDGES 500000
#define HDIM 128
#define CDIM 64
#define GDIM 64

// ---------------- CSR build ----------------

__global__ void k_init_deg(int* __restrict__ deg, int n) {
    int i = blockIdx.x * 256 + threadIdx.x;
    if (i < n) deg[i] = 1;  // self loop
}

__global__ void k_hist(const int* __restrict__ dst, int* __restrict__ deg, int e) {
    int i = blockIdx.x * 256 + threadIdx.x;
    if (i < e) atomicAdd(&deg[dst[i]], 1);
}

__device__ inline int block_scan_incl(int v, int* lds) {
    int lane = threadIdx.x & 63, wid = threadIdx.x >> 6;
#pragma unroll
    for (int off = 1; off < 64; off <<= 1) {
        int nv = __shfl_up(v, off);
        if (lane >= off) v += nv;
    }
    if (lane == 63) lds[wid] = v;
    __syncthreads();
    if (wid == 0) {
        int s = (lane < 16) ? lds[lane] : 0;
#pragma unroll
        for (int off = 1; off < 16; off <<= 1) {
            int nv = __shfl_up(s, off);
            if (lane >= off) s += nv;
        }
        if (lane < 16) lds[lane] = s;
    }
    __syncthreads();
    return (wid > 0) ? v + lds[wid - 1] : v;
}

__global__ __launch_bounds__(1024) void k_scan1(const int* __restrict__ deg, int* __restrict__ incl,
                                                int* __restrict__ bsums, int n) {
    __shared__ int lds[16];
    int i = blockIdx.x * 1024 + threadIdx.x;
    int v = (i < n) ? deg[i] : 0;
    int s = block_scan_incl(v, lds);
    if (i < n) incl[i] = s;
    if (threadIdx.x == 1023) bsums[blockIdx.x] = s;
}

__global__ void k_scan2(int* __restrict__ bsums, int nb) {
    int lane = threadIdx.x;
    int v = (lane < nb) ? bsums[lane] : 0;
#pragma unroll
    for (int off = 1; off < 64; off <<= 1) {
        int nv = __shfl_up(v, off);
        if (lane >= off) v += nv;
    }
    if (lane < nb) bsums[lane] = v;
}

__global__ __launch_bounds__(1024) void k_scan3(const int* __restrict__ incl, const int* __restrict__ deg,
                                                const int* __restrict__ bsums, int* __restrict__ row_ptr,
                                                int* __restrict__ cursor, int n) {
    int i = blockIdx.x * 1024 + threadIdx.x;
    if (i >= n) return;
    int off = (blockIdx.x > 0) ? bsums[blockIdx.x - 1] : 0;
    int inc = incl[i] + off;
    row_ptr[i + 1] = inc;
    cursor[i] = inc - deg[i];
    if (i == 0) row_ptr[0] = 0;
}

__global__ void k_scatter_self(int* __restrict__ cursor, int* __restrict__ col, int n) {
    int i = blockIdx.x * 256 + threadIdx.x;
    if (i < n) { int p = atomicAdd(&cursor[i], 1); col[p] = i; }
}

__global__ void k_scatter_edges(const int* __restrict__ src, const int* __restrict__ dst,
                                int* __restrict__ cursor, int* __restrict__ col, int e) {
    int i = blockIdx.x * 256 + threadIdx.x;
    if (i < e) { int p = atomicAdd(&cursor[dst[i]], 1); col[p] = src[i]; }
}

// ---------------- GEMM (fp32, K=128) ----------------
// MODE 0: plain store. MODE 1: relu(acc + bias). MODE 2: acc + bias.

template <int NOUT, int MODE>
__global__ __launch_bounds__(256) void k_gemm(const float* __restrict__ A, const float* __restrict__ W,
                                              const float* __restrict__ bias, float* __restrict__ Out,
                                              int M) {
    constexpr int TN = NOUT / 16;  // 8 or 4 cols per thread
    __shared__ float As[64][33];
    __shared__ float Bs[32][NOUT + 4];
    const int tid = threadIdx.x;
    const int tx = tid & 15, ty = tid >> 4;
    const int row0 = blockIdx.x * 64;

    float acc[4][TN];
#pragma unroll
    for (int i = 0; i < 4; i++)
#pragma unroll
        for (int j = 0; j < TN; j++) acc[i][j] = 0.f;

    for (int kc = 0; kc < 128; kc += 32) {
        // load A tile: 64 rows x 32 k = 512 float4
#pragma unroll
        for (int t = 0; t < 2; t++) {
            int f = t * 256 + tid;
            int r = f >> 3, kq = f & 7;
            int row = row0 + r;
            float4 v = make_float4(0.f, 0.f, 0.f, 0.f);
            if (row < M) v = *reinterpret_cast<const float4*>(A + (size_t)row * 128 + kc + kq * 4);
            As[r][kq * 4 + 0] = v.x; As[r][kq * 4 + 1] = v.y;
            As[r][kq * 4 + 2] = v.z; As[r][kq * 4 + 3] = v.w;
        }
        // load W tile: 32 k x NOUT
        constexpr int NB4 = 32 * NOUT / 4;
#pragma unroll
        for (int t = 0; t < NB4 / 256; t++) {
            int f = t * 256 + tid;
            int kr = f / (NOUT / 4), cq = f % (NOUT / 4);
            float4 v = *reinterpret_cast<const float4*>(W + (size_t)(kc + kr) * NOUT + cq * 4);
            *reinterpret_cast<float4*>(&Bs[kr][cq * 4]) = v;
        }
        __syncthreads();
#pragma unroll
        for (int k = 0; k < 32; k++) {
            float a[4], b[TN];
#pragma unroll
            for (int i = 0; i < 4; i++) a[i] = As[ty * 4 + i][k];
#pragma unroll
            for (int j = 0; j < TN; j++) b[j] = Bs[k][tx * TN + j];
#pragma unroll
            for (int i = 0; i < 4; i++)
#pragma unroll
                for (int j = 0; j < TN; j++) acc[i][j] += a[i] * b[j];
        }
        __syncthreads();
    }
#pragma unroll
    for (int i = 0; i < 4; i++) {
        int row = row0 + ty * 4 + i;
        if (row >= M) continue;
#pragma unroll
        for (int j = 0; j < TN; j++) {
            int c = tx * TN + j;
            float v = acc[i][j];
            if (MODE == 1) v = fmaxf(v + bias[c], 0.f);
            if (MODE == 2) v = v + bias[c];
            Out[(size_t)row * NOUT + c] = v;
        }
    }
}

// ---------------- attention logits per node ----------------

__global__ __launch_bounds__(256) void k_alpha(const float* __restrict__ h, const float* __restrict__ a_s,
                                               const float* __restrict__ a_d, float* __restrict__ alpha_s,
                                               float* __restrict__ alpha_d, int n) {
    int w = blockIdx.x * 4 + (threadIdx.x >> 6);
    int lane = threadIdx.x & 63;
    if (w >= n) return;
    const float* hr = h + (size_t)w * HDIM;
    float h0 = hr[lane], h1 = hr[lane + 64];
    float ss = h0 * a_s[lane] + h1 * a_s[lane + 64];
    float sd = h0 * a_d[lane] + h1 * a_d[lane + 64];
#pragma unroll
    for (int off = 32; off; off >>= 1) {
        ss += __shfl_xor(ss, off);
        sd += __shfl_xor(sd, off);
    }
    if (lane == 0) { alpha_s[w] = ss; alpha_d[w] = sd; }
}

// ---------------- segment softmax + aggregate + bias + ELU ----------------

__global__ __launch_bounds__(256) void k_aggregate(const float* __restrict__ h,
                                                   const float* __restrict__ alpha_s,
                                                   const float* __restrict__ alpha_d,
                                                   const int* __restrict__ row_ptr,
                                                   const int* __restrict__ col,
                                                   const float* __restrict__ bias,
                                                   float* __restrict__ out, int n) {
    int w = blockIdx.x * 4 + (threadIdx.x >> 6);
    int lane = threadIdx.x & 63;
    if (w >= n) return;
    int beg = row_ptr[w], end = row_ptr[w + 1];
    float ad = alpha_d[w];
    float m = -1e30f;
    for (int i = beg + lane; i < end; i += 64) {
        float e = alpha_s[col[i]] + ad;
        e = (e > 0.f) ? e : 0.2f * e;
        m = fmaxf(m, e);
    }
#pragma unroll
    for (int off = 32; off; off >>= 1) m = fmaxf(m, __shfl_xor(m, off));

    float denom = 0.f, acc0 = 0.f, acc1 = 0.f;
    for (int i = beg; i < end; ++i) {
        int s = col[i];
        float e = alpha_s[s] + ad;
        e = (e > 0.f) ? e : 0.2f * e;
        float ex = expf(e - m);
        denom += ex;
        const float* hr = h + (size_t)s * HDIM;
        acc0 += ex * hr[lane];
        acc1 += ex * hr[lane + 64];
    }
    float inv = 1.f / denom;
    float v0 = acc0 * inv + bias[lane];
    float v1 = acc1 * inv + bias[lane + 64];
    v0 = (v0 > 0.f) ? v0 : expf(v0) - 1.f;
    v1 = (v1 > 0.f) ? v1 : expf(v1) - 1.f;
    out[(size_t)w * HDIM + lane] = v0;
    out[(size_t)w * HDIM + 64 + lane] = v1;
}

// ---------------- pooling (batch is sorted) ----------------

__global__ void k_zero(float* __restrict__ p, int n) {
    int i = blockIdx.x * 256 + threadIdx.x;
    if (i < n) p[i] = 0.f;
}

__global__ __launch_bounds__(64) void k_pool(const float* __restrict__ u, const int* __restrict__ batch,
                                             float* __restrict__ p, int n) {
    int lane = threadIdx.x;
    int base = blockIdx.x * 256;
    int endn = min(base + 256, n);
    float acc = 0.f;
    int cur = -1;
    for (int nn = base; nn < endn; ++nn) {
        int g = batch[nn];
        if (g != cur) {
            if (cur >= 0) atomicAdd(&p[cur * CDIM + lane], acc);
            acc = 0.f;
            cur = g;
        }
        acc += u[(size_t)nn * CDIM + lane];
    }
    if (cur >= 0) atomicAdd(&p[cur * CDIM + lane], acc);
}

// ---------------- final p1^T @ p2 ----------------

__global__ __launch_bounds__(64) void k_final(const float* __restrict__ p1, const float* __restrict__ p2,
                                              float* __restrict__ out) {
    int i = blockIdx.x;    // row in C
    int j = threadIdx.x;   // col in C
    float s = 0.f;
    for (int g = 0; g < GDIM; ++g) s += p1[g * CDIM + i] * p2[g * CDIM + j];
    out[i * CDIM + j] = s;
}

// ---------------- host side ----------------

static inline size_t align_up(size_t x, size_t a) { return (x + a - 1) & ~(a - 1); }

struct Ws {
    float *H, *Y, *alpha_s, *alpha_d, *p1, *p2;
    int *deg, *incl, *row_ptr, *cursor, *col, *bsums;
};

static Ws carve(void* ws) {
    char* p = (char*)ws;
    size_t off = 0;
    Ws w;
    auto take = [&](size_t bytes) {
        char* r = p + off;
        off = align_up(off + bytes, 256);
        return r;
    };
    w.H = (float*)take((size_t)NNODES * HDIM * 4);
    w.Y = (float*)take((size_t)NNODES * HDIM * 4);
    w.alpha_s = (float*)take((size_t)NNODES * 4);
    w.alpha_d = (float*)take((size_t)NNODES * 4);
    w.deg = (int*)take((size_t)NNODES * 4);
    w.incl = (int*)take((size_t)NNODES * 4);
    w.row_ptr = (int*)take((size_t)(NNODES + 1) * 4);
    w.cursor = (int*)take((size_t)NNODES * 4);
    w.col = (int*)take((size_t)(NEDGES + NNODES) * 4);
    w.bsums = (int*)take(1024);
    w.p1 = (float*)take((size_t)GDIM * CDIM * 4);
    w.p2 = (float*)take((size_t)GDIM * CDIM * 4);
    return w;
}

static void run_branch(const float* x, const int* ei, const int* batch, const float* convW,
                       const float* att_s, const float* att_d, const float* conv_b,
                       const float* w1, const float* b1, const float* w2, const float* b2,
                       const Ws& w, float* p, hipStream_t stream) {
    const int N = NNODES, E = NEDGES;
    const int* src = ei;
    const int* dst = ei + E;

    k_init_deg<<<(N + 255) / 256, 256, 0, stream>>>(w.deg, N);
    k_hist<<<(E + 255) / 256, 256, 0, stream>>>(dst, w.deg, E);
    int nb = (N + 1023) / 1024;
    k_scan1<<<nb, 1024, 0, stream>>>(w.deg, w.incl, w.bsums, N);
    k_scan2<<<1, 64, 0, stream>>>(w.bsums, nb);
    k_scan3<<<nb, 1024, 0, stream>>>(w.incl, w.deg, w.bsums, w.row_ptr, w.cursor, N);
    k_scatter_self<<<(N + 255) / 256, 256, 0, stream>>>(w.cursor, w.col, N);
    k_scatter_edges<<<(E + 255) / 256, 256, 0, stream>>>(src, dst, w.cursor, w.col, E);

    // conv layer 0
    k_gemm<HDIM, 0><<<(N + 63) / 64, 256, 0, stream>>>(x, convW, nullptr, w.H, N);
    k_alpha<<<(N + 3) / 4, 256, 0, stream>>>(w.H, att_s, att_d, w.alpha_s, w.alpha_d, N);
    k_aggregate<<<(N + 3) / 4, 256, 0, stream>>>(w.H, w.alpha_s, w.alpha_d, w.row_ptr, w.col,
                                                 conv_b, w.Y, N);
    // conv layer 1
    k_gemm<HDIM, 0><<<(N + 63) / 64, 256, 0, stream>>>(w.Y, convW + HDIM * HDIM, nullptr, w.H, N);
    k_alpha<<<(N + 3) / 4, 256, 0, stream>>>(w.H, att_s + HDIM, att_d + HDIM, w.alpha_s, w.alpha_d, N);
    k_aggregate<<<(N + 3) / 4, 256, 0, stream>>>(w.H, w.alpha_s, w.alpha_d, w.row_ptr, w.col,
                                                 conv_b + HDIM, w.Y, N);
    // MLP: t = relu(z @ w1 + b1) -> H ; u = t @ w2 + b2 -> Y (as [N,64])
    k_gemm<HDIM, 1><<<(N + 63) / 64, 256, 0, stream>>>(w.Y, w1, b1, w.H, N);
    k_gemm<CDIM, 2><<<(N + 63) / 64, 256, 0, stream>>>(w.H, w2, b2, w.Y, N);

    k_zero<<<(GDIM * CDIM + 255) / 256, 256, 0, stream>>>(p, GDIM * CDIM);
    k_pool<<<(N + 255) / 256, 64, 0, stream>>>(w.Y, batch, p, N);
}

extern "C" void kernel_launch(void* const* d_in, const int* in_sizes, int n_in, void* d_out,
                              int out_size, void* d_ws, size_t ws_size, hipStream_t stream) {
    const float* x1      = (const float*)d_in[0];
    const float* x2      = (const float*)d_in[1];
    const float* convW   = (const float*)d_in[2];
    const float* att_src = (const float*)d_in[3];
    const float* att_dst = (const float*)d_in[4];
    const float* conv_b  = (const float*)d_in[5];
    const float* mlp_w1  = (const float*)d_in[6];
    const float* mlp_b1  = (const float*)d_in[7];
    const float* mlp_w2  = (const float*)d_in[8];
    const float* mlp_b2  = (const float*)d_in[9];
    const int* ei1       = (const int*)d_in[10];
    const int* batch1    = (const int*)d_in[11];
    const int* ei2       = (const int*)d_in[12];
    const int* batch2    = (const int*)d_in[13];
    float* out = (float*)d_out;

    Ws w = carve(d_ws);

    run_branch(x1, ei1, batch1, convW, att_src, att_dst, conv_b, mlp_w1, mlp_b1, mlp_w2, mlp_b2,
               w, w.p1, stream);
    run_branch(x2, ei2, batch2, convW, att_src, att_dst, conv_b, mlp_w1, mlp_b1, mlp_w2, mlp_b2,
               w, w.p2, stream);

    k_final<<<CDIM, CDIM, 0, stream>>>(w.p1, w.p2, out);
}

// Round 3
// 717.885 us; speedup vs baseline: 1.2745x; 1.2745x over previous
//
#include <hip/hip_runtime.h>
#include <cstdint>
#include <cstddef>

#define NNODES 50000
#define NEDGES 500000
#define NTOT (NEDGES + NNODES)
#define HDIM 128
#define CDIM 64
#define GDIM 64

typedef __bf16 bf16x8 __attribute__((ext_vector_type(8)));
typedef __bf16 bf16x4 __attribute__((ext_vector_type(4)));
typedef __bf16 bf16x2 __attribute__((ext_vector_type(2)));
typedef float f32x4 __attribute__((ext_vector_type(4)));

// ---------------- CSR build ----------------

__global__ void k_init_deg(int* __restrict__ deg, int n) {
    int i = blockIdx.x * 256 + threadIdx.x;
    if (i < n) deg[i] = 1;  // self loop
}

__global__ void k_hist(const int* __restrict__ dst, int* __restrict__ deg, int e) {
    int i = blockIdx.x * 256 + threadIdx.x;
    if (i < e) atomicAdd(&deg[dst[i]], 1);
}

__device__ inline int block_scan_incl(int v, int* lds) {
    int lane = threadIdx.x & 63, wid = threadIdx.x >> 6;
#pragma unroll
    for (int off = 1; off < 64; off <<= 1) {
        int nv = __shfl_up(v, off);
        if (lane >= off) v += nv;
    }
    if (lane == 63) lds[wid] = v;
    __syncthreads();
    if (wid == 0) {
        int s = (lane < 16) ? lds[lane] : 0;
#pragma unroll
        for (int off = 1; off < 16; off <<= 1) {
            int nv = __shfl_up(s, off);
            if (lane >= off) s += nv;
        }
        if (lane < 16) lds[lane] = s;
    }
    __syncthreads();
    return (wid > 0) ? v + lds[wid - 1] : v;
}

__global__ __launch_bounds__(1024) void k_scan1(const int* __restrict__ deg, int* __restrict__ incl,
                                                int* __restrict__ bsums, int n) {
    __shared__ int lds[16];
    int i = blockIdx.x * 1024 + threadIdx.x;
    int v = (i < n) ? deg[i] : 0;
    int s = block_scan_incl(v, lds);
    if (i < n) incl[i] = s;
    if (threadIdx.x == 1023) bsums[blockIdx.x] = s;
}

__global__ void k_scan2(int* __restrict__ bsums, int nb) {
    int lane = threadIdx.x;
    int v = (lane < nb) ? bsums[lane] : 0;
#pragma unroll
    for (int off = 1; off < 64; off <<= 1) {
        int nv = __shfl_up(v, off);
        if (lane >= off) v += nv;
    }
    if (lane < nb) bsums[lane] = v;
}

__global__ __launch_bounds__(1024) void k_scan3(const int* __restrict__ incl, const int* __restrict__ deg,
                                                const int* __restrict__ bsums, int* __restrict__ row_ptr,
                                                int* __restrict__ cursor, int n) {
    int i = blockIdx.x * 1024 + threadIdx.x;
    if (i >= n) return;
    int off = (blockIdx.x > 0) ? bsums[blockIdx.x - 1] : 0;
    int inc = incl[i] + off;
    row_ptr[i + 1] = inc;
    cursor[i] = inc - deg[i];
    if (i == 0) row_ptr[0] = 0;
}

__global__ void k_scatter_self(int* __restrict__ cursor, int* __restrict__ col, int n) {
    int i = blockIdx.x * 256 + threadIdx.x;
    if (i < n) { int p = atomicAdd(&cursor[i], 1); col[p] = i; }
}

__global__ void k_scatter_edges(const int* __restrict__ src, const int* __restrict__ dst,
                                int* __restrict__ cursor, int* __restrict__ col, int e) {
    int i = blockIdx.x * 256 + threadIdx.x;
    if (i < e) { int p = atomicAdd(&cursor[dst[i]], 1); col[p] = src[i]; }
}

// ---------------- casts ----------------

__global__ void k_cast_x(const float* __restrict__ in, __bf16* __restrict__ out, int n4) {
    int i = blockIdx.x * 256 + threadIdx.x;
    if (i < n4) {
        float4 v = reinterpret_cast<const float4*>(in)[i];
        bf16x4 o;
        o.x = (__bf16)v.x; o.y = (__bf16)v.y; o.z = (__bf16)v.z; o.w = (__bf16)v.w;
        reinterpret_cast<bf16x4*>(out)[i] = o;
    }
}

// in [K][N] fp32 -> out [N][128] bf16 (K==128 always)
__global__ void k_cast_wt(const float* __restrict__ in, __bf16* __restrict__ out, int ncols, int total) {
    int i = blockIdx.x * 256 + threadIdx.x;
    if (i < total) {
        int k = i / ncols, n = i % ncols;
        out[(size_t)n * 128 + k] = (__bf16)in[i];
    }
}

// ---------------- MFMA GEMM: [M,128] bf16 @ Wt[BN][128] bf16 -> out ----------------
// MODE 0: bf16 store. MODE 1: bf16 relu(acc+bias). MODE 2: fp32 acc+bias.

template <int BN, int MODE>
__global__ __launch_bounds__(256) void k_gemm_mfma(const __bf16* __restrict__ A,
                                                   const __bf16* __restrict__ Wt,
                                                   const float* __restrict__ bias,
                                                   void* __restrict__ Out, int M) {
    constexpr int WAVES_N = (BN == 128) ? 2 : 1;
    constexpr int WAVES_M = 4 / WAVES_N;
    constexpr int WM = 64 / WAVES_M;  // 32 or 16
    constexpr int MF = WM / 16;       // 2 or 1
    constexpr int NF = 4;
    __shared__ __align__(16) unsigned short As[64][136];
    __shared__ __align__(16) unsigned short Bs[BN][136];
    const int tid = threadIdx.x;
    const int lane = tid & 63, w = tid >> 6;
    const int row0 = blockIdx.x * 64;

    // stage A (64 rows x 128), 16B chunks
#pragma unroll
    for (int t = 0; t < 4; t++) {
        int ch = t * 256 + tid;
        int r = ch >> 4, cx = ch & 15;
        int grow = row0 + r;
        bf16x8 v = {};
        if (grow < M) v = *reinterpret_cast<const bf16x8*>(A + (size_t)grow * 128 + cx * 8);
        *reinterpret_cast<bf16x8*>(&As[r][cx * 8]) = v;
    }
    // stage B: Wt [BN][128]
#pragma unroll
    for (int t = 0; t < BN / 16; t++) {
        int ch = t * 256 + tid;
        int r = ch >> 4, cx = ch & 15;
        bf16x8 v = *reinterpret_cast<const bf16x8*>(Wt + (size_t)r * 128 + cx * 8);
        *reinterpret_cast<bf16x8*>(&Bs[r][cx * 8]) = v;
    }
    __syncthreads();

    const int wr0 = (w / WAVES_N) * WM;
    const int wc0 = (w % WAVES_N) * 64;
    f32x4 acc[MF][NF] = {};

#pragma unroll
    for (int ks = 0; ks < 4; ks++) {
        const int koff = ks * 32 + (lane >> 4) * 8;
        bf16x8 af[MF], bfr[NF];
#pragma unroll
        for (int mf = 0; mf < MF; mf++)
            af[mf] = *reinterpret_cast<const bf16x8*>(&As[wr0 + mf * 16 + (lane & 15)][koff]);
#pragma unroll
        for (int nf = 0; nf < NF; nf++)
            bfr[nf] = *reinterpret_cast<const bf16x8*>(&Bs[wc0 + nf * 16 + (lane & 15)][koff]);
#pragma unroll
        for (int mf = 0; mf < MF; mf++)
#pragma unroll
            for (int nf = 0; nf < NF; nf++)
                acc[mf][nf] = __builtin_amdgcn_mfma_f32_16x16x32_bf16(af[mf], bfr[nf], acc[mf][nf], 0, 0, 0);
    }

#pragma unroll
    for (int mf = 0; mf < MF; mf++) {
#pragma unroll
        for (int r = 0; r < 4; r++) {
            int row = row0 + wr0 + mf * 16 + (lane >> 4) * 4 + r;
            if (row >= M) continue;
#pragma unroll
            for (int nf = 0; nf < NF; nf++) {
                int colc = wc0 + nf * 16 + (lane & 15);
                float v = acc[mf][nf][r];
                if (MODE == 1) v = fmaxf(v + bias[colc], 0.f);
                if (MODE == 2) v = v + bias[colc];
                if (MODE == 2)
                    reinterpret_cast<float*>(Out)[(size_t)row * BN + colc] = v;
                else
                    reinterpret_cast<__bf16*>(Out)[(size_t)row * BN + colc] = (__bf16)v;
            }
        }
    }
}

// ---------------- attention logits per node (h bf16) ----------------

__global__ __launch_bounds__(256) void k_alpha(const __bf16* __restrict__ h,
                                               const float* __restrict__ a_s,
                                               const float* __restrict__ a_d,
                                               float* __restrict__ alpha_s,
                                               float* __restrict__ alpha_d, int n) {
    int w = blockIdx.x * 4 + (threadIdx.x >> 6);
    int lane = threadIdx.x & 63;
    if (w >= n) return;
    bf16x2 hv = reinterpret_cast<const bf16x2*>(h)[(size_t)w * 64 + lane];
    float h0 = (float)hv.x, h1 = (float)hv.y;
    float ss = h0 * a_s[2 * lane] + h1 * a_s[2 * lane + 1];
    float sd = h0 * a_d[2 * lane] + h1 * a_d[2 * lane + 1];
#pragma unroll
    for (int off = 32; off; off >>= 1) {
        ss += __shfl_xor(ss, off);
        sd += __shfl_xor(sd, off);
    }
    if (lane == 0) { alpha_s[w] = ss; alpha_d[w] = sd; }
}

// ---------------- segment softmax: max + denom + per-edge weights ----------------

__global__ __launch_bounds__(256) void k_maxdenom(const float* __restrict__ alpha_s,
                                                  const float* __restrict__ alpha_d,
                                                  const int* __restrict__ row_ptr,
                                                  const int* __restrict__ col,
                                                  float* __restrict__ wgt,
                                                  float* __restrict__ inv, int n) {
    int w = blockIdx.x * 4 + (threadIdx.x >> 6);
    int lane = threadIdx.x & 63;
    if (w >= n) return;
    int beg = row_ptr[w], end = row_ptr[w + 1];
    float ad = alpha_d[w];
    float m = -1e30f;
    for (int i = beg + lane; i < end; i += 64) {
        float e = alpha_s[col[i]] + ad;
        e = (e > 0.f) ? e : 0.2f * e;
        m = fmaxf(m, e);
    }
#pragma unroll
    for (int off = 32; off; off >>= 1) m = fmaxf(m, __shfl_xor(m, off));
    float den = 0.f;
    for (int i = beg + lane; i < end; i += 64) {
        float e = alpha_s[col[i]] + ad;
        e = (e > 0.f) ? e : 0.2f * e;
        float ex = __expf(e - m);
        wgt[i] = ex;
        den += ex;
    }
#pragma unroll
    for (int off = 32; off; off >>= 1) den += __shfl_xor(den, off);
    if (lane == 0) inv[w] = 1.f / den;
}

// ---------------- aggregate: out = ELU(inv * sum_e wgt_e * h[src_e] + bias) ----------------

__global__ __launch_bounds__(256) void k_aggregate(const __bf16* __restrict__ h,
                                                   const float* __restrict__ wgt,
                                                   const float* __restrict__ inv,
                                                   const int* __restrict__ row_ptr,
                                                   const int* __restrict__ col,
                                                   const float* __restrict__ bias,
                                                   __bf16* __restrict__ out, int n) {
    int w = blockIdx.x * 4 + (threadIdx.x >> 6);
    int lane = threadIdx.x & 63;
    if (w >= n) return;
    int beg = row_ptr[w], end = row_ptr[w + 1];
    const unsigned int* hb = reinterpret_cast<const unsigned int*>(h);
    float a0 = 0.f, a1 = 0.f;
    int i = beg;
    int s = col[i];
    float wv = wgt[i];
    for (;;) {
        int inext = i + 1;
        int s2 = 0; float w2 = 0.f;
        bool more = inext < end;
        if (more) { s2 = col[inext]; w2 = wgt[inext]; }
        unsigned int hbits = hb[(size_t)s * 64 + lane];
        bf16x2 hv = __builtin_bit_cast(bf16x2, hbits);
        a0 += wv * (float)hv.x;
        a1 += wv * (float)hv.y;
        if (!more) break;
        i = inext; s = s2; wv = w2;
    }
    float sc = inv[w];
    float v0 = a0 * sc + bias[2 * lane];
    float v1 = a1 * sc + bias[2 * lane + 1];
    v0 = (v0 > 0.f) ? v0 : __expf(v0) - 1.f;
    v1 = (v1 > 0.f) ? v1 : __expf(v1) - 1.f;
    bf16x2 o;
    o.x = (__bf16)v0; o.y = (__bf16)v1;
    reinterpret_cast<bf16x2*>(out)[(size_t)w * 64 + lane] = o;
}

// ---------------- pooling (batch sorted) ----------------

__global__ void k_zero(float* __restrict__ p, int n) {
    int i = blockIdx.x * 256 + threadIdx.x;
    if (i < n) p[i] = 0.f;
}

__global__ __launch_bounds__(64) void k_pool(const float* __restrict__ u, const int* __restrict__ batch,
                                             float* __restrict__ p, int n) {
    int lane = threadIdx.x;
    int base = blockIdx.x * 64;
    int endn = min(base + 64, n);
    float acc = 0.f;
    int cur = -1;
    for (int nn = base; nn < endn; ++nn) {
        int g = batch[nn];
        if (g != cur) {
            if (cur >= 0) atomicAdd(&p[cur * CDIM + lane], acc);
            acc = 0.f;
            cur = g;
        }
        acc += u[(size_t)nn * CDIM + lane];
    }
    if (cur >= 0) atomicAdd(&p[cur * CDIM + lane], acc);
}

// ---------------- final p1^T @ p2 ----------------

__global__ __launch_bounds__(64) void k_final(const float* __restrict__ p1, const float* __restrict__ p2,
                                              float* __restrict__ out) {
    int i = blockIdx.x;
    int j = threadIdx.x;
    float s = 0.f;
    for (int g = 0; g < GDIM; ++g) s += p1[g * CDIM + i] * p2[g * CDIM + j];
    out[i * CDIM + j] = s;
}

// ---------------- host side ----------------

static inline size_t align_up(size_t x, size_t a) { return (x + a - 1) & ~(a - 1); }

struct Ws {
    __bf16 *Hb, *Yb;
    __bf16 *WtC0, *WtC1, *Wt1, *Wt2;
    float *U, *alpha_s, *alpha_d, *inv, *wgt, *p1, *p2;
    int *deg, *incl, *row_ptr, *cursor, *col, *bsums;
};

static Ws carve(void* ws) {
    char* p = (char*)ws;
    size_t off = 0;
    Ws w;
    auto take = [&](size_t bytes) {
        char* r = p + off;
        off = align_up(off + bytes, 256);
        return r;
    };
    w.Hb = (__bf16*)take((size_t)NNODES * HDIM * 2);
    w.Yb = (__bf16*)take((size_t)NNODES * HDIM * 2);
    w.U = (float*)take((size_t)NNODES * CDIM * 4);
    w.alpha_s = (float*)take((size_t)NNODES * 4);
    w.alpha_d = (float*)take((size_t)NNODES * 4);
    w.inv = (float*)take((size_t)NNODES * 4);
    w.wgt = (float*)take((size_t)NTOT * 4);
    w.deg = (int*)take((size_t)NNODES * 4);
    w.incl = (int*)take((size_t)NNODES * 4);
    w.row_ptr = (int*)take((size_t)(NNODES + 1) * 4);
    w.cursor = (int*)take((size_t)NNODES * 4);
    w.col = (int*)take((size_t)NTOT * 4);
    w.bsums = (int*)take(1024);
    w.WtC0 = (__bf16*)take((size_t)HDIM * HDIM * 2);
    w.WtC1 = (__bf16*)take((size_t)HDIM * HDIM * 2);
    w.Wt1 = (__bf16*)take((size_t)HDIM * HDIM * 2);
    w.Wt2 = (__bf16*)take((size_t)HDIM * CDIM * 2);
    w.p1 = (float*)take((size_t)GDIM * CDIM * 4);
    w.p2 = (float*)take((size_t)GDIM * CDIM * 4);
    return w;
}

static void run_branch(const float* x, const int* ei, const int* batch,
                       const float* att_s, const float* att_d, const float* conv_b,
                       const float* b1, const float* b2,
                       const Ws& w, float* p, hipStream_t stream) {
    const int N = NNODES, E = NEDGES;
    const int* src = ei;
    const int* dst = ei + E;

    k_init_deg<<<(N + 255) / 256, 256, 0, stream>>>(w.deg, N);
    k_hist<<<(E + 255) / 256, 256, 0, stream>>>(dst, w.deg, E);
    int nb = (N + 1023) / 1024;
    k_scan1<<<nb, 1024, 0, stream>>>(w.deg, w.incl, w.bsums, N);
    k_scan2<<<1, 64, 0, stream>>>(w.bsums, nb);
    k_scan3<<<nb, 1024, 0, stream>>>(w.incl, w.deg, w.bsums, w.row_ptr, w.cursor, N);
    k_scatter_self<<<(N + 255) / 256, 256, 0, stream>>>(w.cursor, w.col, N);
    k_scatter_edges<<<(E + 255) / 256, 256, 0, stream>>>(src, dst, w.cursor, w.col, E);

    // cast input to bf16 into Yb
    k_cast_x<<<(N * HDIM / 4 + 255) / 256, 256, 0, stream>>>(x, w.Yb, N * HDIM / 4);

    int gblk = (N + 63) / 64;
    // conv layer 0
    k_gemm_mfma<HDIM, 0><<<gblk, 256, 0, stream>>>(w.Yb, w.WtC0, nullptr, w.Hb, N);
    k_alpha<<<(N + 3) / 4, 256, 0, stream>>>(w.Hb, att_s, att_d, w.alpha_s, w.alpha_d, N);
    k_maxdenom<<<(N + 3) / 4, 256, 0, stream>>>(w.alpha_s, w.alpha_d, w.row_ptr, w.col, w.wgt, w.inv, N);
    k_aggregate<<<(N + 3) / 4, 256, 0, stream>>>(w.Hb, w.wgt, w.inv, w.row_ptr, w.col, conv_b, w.Yb, N);
    // conv layer 1
    k_gemm_mfma<HDIM, 0><<<gblk, 256, 0, stream>>>(w.Yb, w.WtC1, nullptr, w.Hb, N);
    k_alpha<<<(N + 3) / 4, 256, 0, stream>>>(w.Hb, att_s + HDIM, att_d + HDIM, w.alpha_s, w.alpha_d, N);
    k_maxdenom<<<(N + 3) / 4, 256, 0, stream>>>(w.alpha_s, w.alpha_d, w.row_ptr, w.col, w.wgt, w.inv, N);
    k_aggregate<<<(N + 3) / 4, 256, 0, stream>>>(w.Hb, w.wgt, w.inv, w.row_ptr, w.col, conv_b + HDIM, w.Yb, N);
    // MLP
    k_gemm_mfma<HDIM, 1><<<gblk, 256, 0, stream>>>(w.Yb, w.Wt1, b1, w.Hb, N);
    k_gemm_mfma<CDIM, 2><<<gblk, 256, 0, stream>>>(w.Hb, w.Wt2, b2, w.U, N);

    k_zero<<<(GDIM * CDIM + 255) / 256, 256, 0, stream>>>(p, GDIM * CDIM);
    k_pool<<<(N + 63) / 64, 64, 0, stream>>>(w.U, batch, p, N);
}

extern "C" void kernel_launch(void* const* d_in, const int* in_sizes, int n_in, void* d_out,
                              int out_size, void* d_ws, size_t ws_size, hipStream_t stream) {
    const float* x1      = (const float*)d_in[0];
    const float* x2      = (const float*)d_in[1];
    const float* convW   = (const float*)d_in[2];
    const float* att_src = (const float*)d_in[3];
    const float* att_dst = (const float*)d_in[4];
    const float* conv_b  = (const float*)d_in[5];
    const float* mlp_w1  = (const float*)d_in[6];
    const float* mlp_b1  = (const float*)d_in[7];
    const float* mlp_w2  = (const float*)d_in[8];
    const float* mlp_b2  = (const float*)d_in[9];
    const int* ei1       = (const int*)d_in[10];
    const int* batch1    = (const int*)d_in[11];
    const int* ei2       = (const int*)d_in[12];
    const int* batch2    = (const int*)d_in[13];
    float* out = (float*)d_out;

    Ws w = carve(d_ws);

    // weight casts/transposes (Wt layout [ncols][128])
    k_cast_wt<<<(HDIM * HDIM + 255) / 256, 256, 0, stream>>>(convW, w.WtC0, HDIM, HDIM * HDIM);
    k_cast_wt<<<(HDIM * HDIM + 255) / 256, 256, 0, stream>>>(convW + HDIM * HDIM, w.WtC1, HDIM, HDIM * HDIM);
    k_cast_wt<<<(HDIM * HDIM + 255) / 256, 256, 0, stream>>>(mlp_w1, w.Wt1, HDIM, HDIM * HDIM);
    k_cast_wt<<<(HDIM * CDIM + 255) / 256, 256, 0, stream>>>(mlp_w2, w.Wt2, CDIM, HDIM * CDIM);

    run_branch(x1, ei1, batch1, att_src, att_dst, conv_b, mlp_b1, mlp_b2, w, w.p1, stream);
    run_branch(x2, ei2, batch2, att_src, att_dst, conv_b, mlp_b1, mlp_b2, w, w.p2, stream);

    k_final<<<CDIM, CDIM, 0, stream>>>(w.p1, w.p2, out);
}

// Round 4
// 499.977 us; speedup vs baseline: 1.8300x; 1.4358x over previous
//
#include <hip/hip_runtime.h>
#include <cstdint>
#include <cstddef>

#define NNODES 50000
#define NEDGES 500000
#define NTOT (NEDGES + NNODES)
#define HDIM 128
#define CDIM 64
#define GDIM 64

typedef __bf16 bf16x8 __attribute__((ext_vector_type(8)));
typedef __bf16 bf16x2 __attribute__((ext_vector_type(2)));
typedef float f32x4 __attribute__((ext_vector_type(4)));

// ================= CSR build (y = branch) =================

__global__ void k_init_deg(int* __restrict__ degB, size_t sN, int n) {
    int i = blockIdx.x * 256 + threadIdx.x;
    int* deg = degB + blockIdx.y * sN;
    if (i < n) deg[i] = 1;  // self loop
}

__global__ void k_hist(const int* __restrict__ ei0, const int* __restrict__ ei1,
                       int* __restrict__ degB, size_t sN, int e) {
    int i = blockIdx.x * 256 + threadIdx.x;
    const int* dst = (blockIdx.y ? ei1 : ei0) + NEDGES;
    int* deg = degB + blockIdx.y * sN;
    if (i < e) atomicAdd(&deg[dst[i]], 1);
}

__device__ inline int block_scan_incl(int v, int* lds) {
    int lane = threadIdx.x & 63, wid = threadIdx.x >> 6;
#pragma unroll
    for (int off = 1; off < 64; off <<= 1) {
        int nv = __shfl_up(v, off);
        if (lane >= off) v += nv;
    }
    if (lane == 63) lds[wid] = v;
    __syncthreads();
    if (wid == 0) {
        int s = (lane < 16) ? lds[lane] : 0;
#pragma unroll
        for (int off = 1; off < 16; off <<= 1) {
            int nv = __shfl_up(s, off);
            if (lane >= off) s += nv;
        }
        if (lane < 16) lds[lane] = s;
    }
    __syncthreads();
    return (wid > 0) ? v + lds[wid - 1] : v;
}

__global__ __launch_bounds__(1024) void k_scan1(const int* __restrict__ degB, int* __restrict__ inclB,
                                                int* __restrict__ bsumsB, size_t sN, int n) {
    __shared__ int lds[16];
    const int* deg = degB + blockIdx.y * sN;
    int* incl = inclB + blockIdx.y * sN;
    int* bsums = bsumsB + blockIdx.y * 64;
    int i = blockIdx.x * 1024 + threadIdx.x;
    int v = (i < n) ? deg[i] : 0;
    int s = block_scan_incl(v, lds);
    if (i < n) incl[i] = s;
    if (threadIdx.x == 1023) bsums[blockIdx.x] = s;
}

__global__ void k_scan2(int* __restrict__ bsumsB, int nb) {
    int* bsums = bsumsB + blockIdx.y * 64;
    int lane = threadIdx.x;
    int v = (lane < nb) ? bsums[lane] : 0;
#pragma unroll
    for (int off = 1; off < 64; off <<= 1) {
        int nv = __shfl_up(v, off);
        if (lane >= off) v += nv;
    }
    if (lane < nb) bsums[lane] = v;
}

__global__ __launch_bounds__(1024) void k_scan3(const int* __restrict__ inclB, const int* __restrict__ degB,
                                                const int* __restrict__ bsumsB, int* __restrict__ rpB,
                                                int* __restrict__ curB, size_t sN, size_t sNp1, int n) {
    int i = blockIdx.x * 1024 + threadIdx.x;
    if (i >= n) return;
    const int* incl = inclB + blockIdx.y * sN;
    const int* deg = degB + blockIdx.y * sN;
    const int* bsums = bsumsB + blockIdx.y * 64;
    int* row_ptr = rpB + blockIdx.y * sNp1;
    int* cursor = curB + blockIdx.y * sN;
    int off = (blockIdx.x > 0) ? bsums[blockIdx.x - 1] : 0;
    int inc = incl[i] + off;
    row_ptr[i + 1] = inc;
    cursor[i] = inc - deg[i];
    if (i == 0) row_ptr[0] = 0;
}

__global__ void k_scatter_self(int* __restrict__ curB, int2* __restrict__ pkB,
                               size_t sN, size_t sE, int n) {
    int i = blockIdx.x * 256 + threadIdx.x;
    int* cursor = curB + blockIdx.y * sN;
    int2* pk = pkB + blockIdx.y * sE;
    if (i < n) { int p = atomicAdd(&cursor[i], 1); pk[p].x = i; }
}

__global__ void k_scatter_edges(const int* __restrict__ ei0, const int* __restrict__ ei1,
                                int* __restrict__ curB, int2* __restrict__ pkB,
                                size_t sN, size_t sE, int e) {
    int i = blockIdx.x * 256 + threadIdx.x;
    const int* eis = (blockIdx.y ? ei1 : ei0);
    const int* src = eis;
    const int* dst = eis + NEDGES;
    int* cursor = curB + blockIdx.y * sN;
    int2* pk = pkB + blockIdx.y * sE;
    if (i < e) { int p = atomicAdd(&cursor[dst[i]], 1); pk[p].x = src[i]; }
}

// ================= weight cast: in [nmat][128][ncols] f32 -> out [nmat][ncols][128] bf16 =================

__global__ void k_cast_wt(const float* __restrict__ in, __bf16* __restrict__ out, int ncols, int total) {
    int i = blockIdx.x * 256 + threadIdx.x;
    if (i < total) {
        int per = 128 * ncols;
        int mat = i / per, rem = i % per;
        int k = rem / ncols, n = rem % ncols;
        out[(size_t)mat * per + (size_t)n * 128 + k] = (__bf16)in[i];
    }
}

// ================= MFMA GEMM: [M,128] @ Wt[BN][128] -> [M,BN] bf16 =================
// MODE 0: plain. MODE 1: relu(acc+bias). MODE 2: acc+bias.  AF32: A is f32 (x input)

template <int BN, int MODE, bool AF32>
__global__ __launch_bounds__(256) void k_gemm_mfma(const float* __restrict__ x0,
                                                   const float* __restrict__ x1,
                                                   const __bf16* __restrict__ Ab, size_t As_,
                                                   const __bf16* __restrict__ Wt,
                                                   const float* __restrict__ bias,
                                                   __bf16* __restrict__ OutB, size_t Os_, int M) {
    constexpr int WAVES_N = (BN == 128) ? 2 : 1;
    constexpr int WAVES_M = 4 / WAVES_N;
    constexpr int WM = 64 / WAVES_M;  // 32 or 16
    constexpr int MF = WM / 16;       // 2 or 1
    constexpr int NF = 4;
    __shared__ __align__(16) unsigned short As[64][136];
    __shared__ __align__(16) unsigned short Bs[BN][136];
    const int tid = threadIdx.x;
    const int lane = tid & 63, w = tid >> 6;
    const int row0 = blockIdx.x * 64;
    __bf16* Out = OutB + blockIdx.y * Os_;

    // stage A (64 rows x 128)
#pragma unroll
    for (int t = 0; t < 4; t++) {
        int ch = t * 256 + tid;
        int r = ch >> 4, cx = ch & 15;
        int grow = row0 + r;
        bf16x8 v = {};
        if (grow < M) {
            if (AF32) {
                const float* Ap = (blockIdx.y ? x1 : x0) + (size_t)grow * 128 + cx * 8;
                float4 f0 = *reinterpret_cast<const float4*>(Ap);
                float4 f1 = *reinterpret_cast<const float4*>(Ap + 4);
                v[0] = (__bf16)f0.x; v[1] = (__bf16)f0.y; v[2] = (__bf16)f0.z; v[3] = (__bf16)f0.w;
                v[4] = (__bf16)f1.x; v[5] = (__bf16)f1.y; v[6] = (__bf16)f1.z; v[7] = (__bf16)f1.w;
            } else {
                v = *reinterpret_cast<const bf16x8*>(Ab + blockIdx.y * As_ + (size_t)grow * 128 + cx * 8);
            }
        }
        *reinterpret_cast<bf16x8*>(&As[r][cx * 8]) = v;
    }
    // stage B
#pragma unroll
    for (int t = 0; t < BN / 16; t++) {
        int ch = t * 256 + tid;
        int r = ch >> 4, cx = ch & 15;
        bf16x8 v = *reinterpret_cast<const bf16x8*>(Wt + (size_t)r * 128 + cx * 8);
        *reinterpret_cast<bf16x8*>(&Bs[r][cx * 8]) = v;
    }
    __syncthreads();

    const int wr0 = (w / WAVES_N) * WM;
    const int wc0 = (w % WAVES_N) * 64;
    f32x4 acc[MF][NF] = {};

#pragma unroll
    for (int ks = 0; ks < 4; ks++) {
        const int koff = ks * 32 + (lane >> 4) * 8;
        bf16x8 af[MF], bfr[NF];
#pragma unroll
        for (int mf = 0; mf < MF; mf++)
            af[mf] = *reinterpret_cast<const bf16x8*>(&As[wr0 + mf * 16 + (lane & 15)][koff]);
#pragma unroll
        for (int nf = 0; nf < NF; nf++)
            bfr[nf] = *reinterpret_cast<const bf16x8*>(&Bs[wc0 + nf * 16 + (lane & 15)][koff]);
#pragma unroll
        for (int mf = 0; mf < MF; mf++)
#pragma unroll
            for (int nf = 0; nf < NF; nf++)
                acc[mf][nf] = __builtin_amdgcn_mfma_f32_16x16x32_bf16(af[mf], bfr[nf], acc[mf][nf], 0, 0, 0);
    }

#pragma unroll
    for (int mf = 0; mf < MF; mf++) {
#pragma unroll
        for (int r = 0; r < 4; r++) {
            int row = row0 + wr0 + mf * 16 + (lane >> 4) * 4 + r;
            if (row >= M) continue;
#pragma unroll
            for (int nf = 0; nf < NF; nf++) {
                int colc = wc0 + nf * 16 + (lane & 15);
                float v = acc[mf][nf][r];
                if (MODE == 1) v = fmaxf(v + bias[colc], 0.f);
                if (MODE == 2) v = v + bias[colc];
                Out[(size_t)row * BN + colc] = (__bf16)v;
            }
        }
    }
}

// ================= attention logits =================

__global__ __launch_bounds__(256) void k_alpha(const __bf16* __restrict__ hB, size_t hS,
                                               const float* __restrict__ a_s,
                                               const float* __restrict__ a_d,
                                               float* __restrict__ asB, float* __restrict__ adB,
                                               size_t aS, int n) {
    int w = blockIdx.x * 4 + (threadIdx.x >> 6);
    int lane = threadIdx.x & 63;
    if (w >= n) return;
    const __bf16* h = hB + blockIdx.y * hS;
    bf16x2 hv = reinterpret_cast<const bf16x2*>(h)[(size_t)w * 64 + lane];
    float h0 = (float)hv.x, h1 = (float)hv.y;
    float ss = h0 * a_s[2 * lane] + h1 * a_s[2 * lane + 1];
    float sd = h0 * a_d[2 * lane] + h1 * a_d[2 * lane + 1];
#pragma unroll
    for (int off = 32; off; off >>= 1) {
        ss += __shfl_xor(ss, off);
        sd += __shfl_xor(sd, off);
    }
    if (lane == 0) { (asB + blockIdx.y * aS)[w] = ss; (adB + blockIdx.y * aS)[w] = sd; }
}

// ================= segment softmax -> normalized weights into pk.y =================

__global__ __launch_bounds__(256) void k_maxdenom(const float* __restrict__ asB,
                                                  const float* __restrict__ adB, size_t aS,
                                                  const int* __restrict__ rpB, size_t sNp1,
                                                  int2* __restrict__ pkB, size_t sE, int n) {
    int w = blockIdx.x * 4 + (threadIdx.x >> 6);
    int lane = threadIdx.x & 63;
    if (w >= n) return;
    const float* alpha_s = asB + blockIdx.y * aS;
    const int* row_ptr = rpB + blockIdx.y * sNp1;
    int2* pk = pkB + blockIdx.y * sE;
    int beg = row_ptr[w], end = row_ptr[w + 1];
    float ad = (adB + blockIdx.y * aS)[w];
    int deg = end - beg;

    if (deg <= 64) {
        int i = beg + lane;
        bool v = i < end;
        float e = -1e30f;
        if (v) {
            int s = pk[i].x;
            e = alpha_s[s] + ad;
            e = (e > 0.f) ? e : 0.2f * e;
        }
        float m = e;
#pragma unroll
        for (int off = 32; off; off >>= 1) m = fmaxf(m, __shfl_xor(m, off));
        float ex = v ? __expf(e - m) : 0.f;
        float den = ex;
#pragma unroll
        for (int off = 32; off; off >>= 1) den += __shfl_xor(den, off);
        if (v) pk[i].y = __float_as_int(ex / den);
    } else {
        float m = -1e30f;
        for (int i = beg + lane; i < end; i += 64) {
            float e = alpha_s[pk[i].x] + ad;
            e = (e > 0.f) ? e : 0.2f * e;
            m = fmaxf(m, e);
        }
#pragma unroll
        for (int off = 32; off; off >>= 1) m = fmaxf(m, __shfl_xor(m, off));
        float den = 0.f;
        for (int i = beg + lane; i < end; i += 64) {
            float e = alpha_s[pk[i].x] + ad;
            e = (e > 0.f) ? e : 0.2f * e;
            den += __expf(e - m);
        }
#pragma unroll
        for (int off = 32; off; off >>= 1) den += __shfl_xor(den, off);
        float rinv = 1.f / den;
        for (int i = beg + lane; i < end; i += 64) {
            float e = alpha_s[pk[i].x] + ad;
            e = (e > 0.f) ? e : 0.2f * e;
            pk[i].y = __float_as_int(__expf(e - m) * rinv);
        }
    }
}

// ================= aggregate: 16 lanes/row (16B), 4 edges per gather instr =================

__global__ __launch_bounds__(256) void k_aggregate(const __bf16* __restrict__ hB, size_t hS,
                                                   const int2* __restrict__ pkB, size_t sE,
                                                   const int* __restrict__ rpB, size_t sNp1,
                                                   const float* __restrict__ bias,
                                                   __bf16* __restrict__ outB, size_t oS, int n) {
    int node = blockIdx.x * 4 + (threadIdx.x >> 6);
    int lane = threadIdx.x & 63;
    if (node >= n) return;
    const bf16x8* h8 = reinterpret_cast<const bf16x8*>(hB + blockIdx.y * hS);
    const int2* pk = pkB + blockIdx.y * sE;
    const int* row_ptr = rpB + blockIdx.y * sNp1;
    int sub = lane >> 4, fo = lane & 15;
    int beg = row_ptr[node], end = row_ptr[node + 1];

    float acc[8] = {0.f, 0.f, 0.f, 0.f, 0.f, 0.f, 0.f, 0.f};
    int i = beg + sub;
    bool v = i < end;
    int2 pv = v ? pk[i] : make_int2(0, 0);
    int nIter = (end - beg + 3) >> 2;
    for (int t = 0; t < nIter; ++t) {
        int inx = i + 4;
        bool vn = inx < end;
        int2 pn = vn ? pk[inx] : make_int2(0, 0);
        float wv = __int_as_float(pv.y);  // 0.0f when invalid
        bf16x8 hv = h8[(size_t)pv.x * 16 + fo];
#pragma unroll
        for (int k = 0; k < 8; k++) acc[k] += wv * (float)hv[k];
        i = inx; v = vn; pv = pn;
    }
#pragma unroll
    for (int k = 0; k < 8; k++) {
        acc[k] += __shfl_xor(acc[k], 16);
        acc[k] += __shfl_xor(acc[k], 32);
    }
    if (sub == 0) {
        float4 b0 = reinterpret_cast<const float4*>(bias)[fo * 2];
        float4 b1 = reinterpret_cast<const float4*>(bias)[fo * 2 + 1];
        float vb[8] = {acc[0] + b0.x, acc[1] + b0.y, acc[2] + b0.z, acc[3] + b0.w,
                       acc[4] + b1.x, acc[5] + b1.y, acc[6] + b1.z, acc[7] + b1.w};
        bf16x8 o;
#pragma unroll
        for (int k = 0; k < 8; k++) {
            float x = vb[k];
            x = (x > 0.f) ? x : __expf(x) - 1.f;
            o[k] = (__bf16)x;
        }
        reinterpret_cast<bf16x8*>(outB + blockIdx.y * oS)[(size_t)node * 16 + fo] = o;
    }
}

// ================= pooling (batch sorted), U is bf16 [N,64] =================

__global__ void k_zero(float* __restrict__ p, int n) {
    int i = blockIdx.x * 256 + threadIdx.x;
    if (i < n) p[i] = 0.f;
}

__global__ __launch_bounds__(64) void k_pool(const __bf16* __restrict__ uB, size_t uS,
                                             const int* __restrict__ bat0, const int* __restrict__ bat1,
                                             float* __restrict__ pB, size_t pS, int n) {
    int lane = threadIdx.x;
    const __bf16* u = uB + blockIdx.y * uS;
    const int* batch = blockIdx.y ? bat1 : bat0;
    float* p = pB + blockIdx.y * pS;
    int base = blockIdx.x * 64;
    int endn = min(base + 64, n);
    float acc = 0.f;
    int cur = -1;
    for (int nn = base; nn < endn; ++nn) {
        int g = batch[nn];
        if (g != cur) {
            if (cur >= 0) atomicAdd(&p[cur * CDIM + lane], acc);
            acc = 0.f;
            cur = g;
        }
        acc += (float)u[(size_t)nn * CDIM + lane];
    }
    if (cur >= 0) atomicAdd(&p[cur * CDIM + lane], acc);
}

// ================= final p1^T @ p2 =================

__global__ __launch_bounds__(64) void k_final(const float* __restrict__ p, float* __restrict__ out) {
    int i = blockIdx.x;
    int j = threadIdx.x;
    const float* p1 = p;
    const float* p2 = p + GDIM * CDIM;
    float s = 0.f;
    for (int g = 0; g < GDIM; ++g) s += p1[g * CDIM + i] * p2[g * CDIM + j];
    out[i * CDIM + j] = s;
}

// ================= host side =================

static inline size_t align_up(size_t x, size_t a) { return (x + a - 1) & ~(a - 1); }

struct Ws {
    __bf16 *Hb, *Yb, *U;
    __bf16 *WtC, *Wt1, *Wt2;
    float *alpha_s, *alpha_d, *p;
    int *deg, *incl, *row_ptr, *cursor, *bsums;
    int2* pk;
    // branch strides (elements); 0 in sequential mode
    size_t sNH, sNC, sN, sNp1, sE;
    size_t need;
};

static Ws carve(void* ws, bool combined) {
    char* p = (char*)ws;
    size_t off = 0;
    Ws w;
    int nb = combined ? 2 : 1;
    auto take = [&](size_t bytes) {
        char* r = p + off;
        off = align_up(off + bytes, 256);
        return r;
    };
    w.Hb = (__bf16*)take((size_t)nb * NNODES * HDIM * 2);
    w.Yb = (__bf16*)take((size_t)nb * NNODES * HDIM * 2);
    w.U = (__bf16*)take((size_t)nb * NNODES * CDIM * 2);
    w.alpha_s = (float*)take((size_t)nb * NNODES * 4);
    w.alpha_d = (float*)take((size_t)nb * NNODES * 4);
    w.pk = (int2*)take((size_t)nb * NTOT * 8);
    w.deg = (int*)take((size_t)nb * NNODES * 4);
    w.incl = (int*)take((size_t)nb * NNODES * 4);
    w.row_ptr = (int*)take((size_t)nb * (NNODES + 1) * 4);
    w.cursor = (int*)take((size_t)nb * NNODES * 4);
    w.bsums = (int*)take((size_t)2 * 64 * 4);
    w.WtC = (__bf16*)take((size_t)2 * HDIM * HDIM * 2);
    w.Wt1 = (__bf16*)take((size_t)HDIM * HDIM * 2);
    w.Wt2 = (__bf16*)take((size_t)HDIM * CDIM * 2);
    w.p = (float*)take((size_t)2 * GDIM * CDIM * 4);
    w.need = off;
    size_t s = combined ? 1 : 0;
    w.sNH = s * (size_t)NNODES * HDIM;
    w.sNC = s * (size_t)NNODES * CDIM;
    w.sN = s * (size_t)NNODES;
    w.sNp1 = s * (size_t)(NNODES + 1);
    w.sE = s * (size_t)NTOT;
    return w;
}

// one pipeline pass; in combined mode yc=2 and inputs are both branches,
// in sequential mode yc=1 and both input slots point at the same branch.
static void pipeline(const Ws& w, const float* xA, const float* xB,
                     const int* eiA, const int* eiB,
                     const int* batA, const int* batB,
                     const float* att_s, const float* att_d, const float* conv_b,
                     const float* b1, const float* b2,
                     float* pbase, size_t pstride, int yc, hipStream_t stream) {
    const int N = NNODES, E = NEDGES;
    dim3 gN((N + 255) / 256, yc), gE((E + 255) / 256, yc);
    int nb = (N + 1023) / 1024;
    dim3 gS(nb, yc), g1(1, yc);
    dim3 gW((N + 3) / 4, yc);
    dim3 gG((N + 63) / 64, yc);
    dim3 gP((N + 63) / 64, yc);

    k_init_deg<<<gN, 256, 0, stream>>>(w.deg, w.sN, N);
    k_hist<<<gE, 256, 0, stream>>>(eiA, eiB, w.deg, w.sN, E);
    k_scan1<<<gS, 1024, 0, stream>>>(w.deg, w.incl, w.bsums, w.sN, N);
    k_scan2<<<g1, 64, 0, stream>>>(w.bsums, nb);
    k_scan3<<<gS, 1024, 0, stream>>>(w.incl, w.deg, w.bsums, w.row_ptr, w.cursor, w.sN, w.sNp1, N);
    k_scatter_self<<<gN, 256, 0, stream>>>(w.cursor, w.pk, w.sN, w.sE, N);
    k_scatter_edges<<<gE, 256, 0, stream>>>(eiA, eiB, w.cursor, w.pk, w.sN, w.sE, E);

    // conv layer 0 (A = x fp32, fused cast)
    k_gemm_mfma<HDIM, 0, true><<<gG, 256, 0, stream>>>(xA, xB, nullptr, 0, w.WtC, nullptr, w.Hb, w.sNH, N);
    k_alpha<<<gW, 256, 0, stream>>>(w.Hb, w.sNH, att_s, att_d, w.alpha_s, w.alpha_d, w.sN, N);
    k_maxdenom<<<gW, 256, 0, stream>>>(w.alpha_s, w.alpha_d, w.sN, w.row_ptr, w.sNp1, w.pk, w.sE, N);
    k_aggregate<<<gW, 256, 0, stream>>>(w.Hb, w.sNH, w.pk, w.sE, w.row_ptr, w.sNp1, conv_b, w.Yb, w.sNH, N);
    // conv layer 1
    k_gemm_mfma<HDIM, 0, false><<<gG, 256, 0, stream>>>(nullptr, nullptr, w.Yb, w.sNH,
                                                        w.WtC + HDIM * HDIM, nullptr, w.Hb, w.sNH, N);
    k_alpha<<<gW, 256, 0, stream>>>(w.Hb, w.sNH, att_s + HDIM, att_d + HDIM, w.alpha_s, w.alpha_d, w.sN, N);
    k_maxdenom<<<gW, 256, 0, stream>>>(w.alpha_s, w.alpha_d, w.sN, w.row_ptr, w.sNp1, w.pk, w.sE, N);
    k_aggregate<<<gW, 256, 0, stream>>>(w.Hb, w.sNH, w.pk, w.sE, w.row_ptr, w.sNp1, conv_b + HDIM, w.Yb, w.sNH, N);
    // MLP
    k_gemm_mfma<HDIM, 1, false><<<gG, 256, 0, stream>>>(nullptr, nullptr, w.Yb, w.sNH, w.Wt1, b1, w.Hb, w.sNH, N);
    k_gemm_mfma<CDIM, 2, false><<<gG, 256, 0, stream>>>(nullptr, nullptr, w.Hb, w.sNH, w.Wt2, b2, w.U, w.sNC, N);

    k_pool<<<gP, 64, 0, stream>>>(w.U, w.sNC, batA, batB, pbase, pstride, N);
}

extern "C" void kernel_launch(void* const* d_in, const int* in_sizes, int n_in, void* d_out,
                              int out_size, void* d_ws, size_t ws_size, hipStream_t stream) {
    const float* x1      = (const float*)d_in[0];
    const float* x2      = (const float*)d_in[1];
    const float* convW   = (const float*)d_in[2];
    const float* att_src = (const float*)d_in[3];
    const float* att_dst = (const float*)d_in[4];
    const float* conv_b  = (const float*)d_in[5];
    const float* mlp_w1  = (const float*)d_in[6];
    const float* mlp_b1  = (const float*)d_in[7];
    const float* mlp_w2  = (const float*)d_in[8];
    const float* mlp_b2  = (const float*)d_in[9];
    const int* ei1       = (const int*)d_in[10];
    const int* batch1    = (const int*)d_in[11];
    const int* ei2       = (const int*)d_in[12];
    const int* batch2    = (const int*)d_in[13];
    float* out = (float*)d_out;

    // decide layout from available workspace (deterministic across calls)
    Ws wc = carve(d_ws, true);
    bool combined = ws_size >= wc.need;
    Ws w = combined ? wc : carve(d_ws, false);

    // weight casts (shared)
    k_cast_wt<<<(2 * HDIM * HDIM + 255) / 256, 256, 0, stream>>>(convW, w.WtC, HDIM, 2 * HDIM * HDIM);
    k_cast_wt<<<(HDIM * HDIM + 255) / 256, 256, 0, stream>>>(mlp_w1, w.Wt1, HDIM, HDIM * HDIM);
    k_cast_wt<<<(HDIM * CDIM + 255) / 256, 256, 0, stream>>>(mlp_w2, w.Wt2, CDIM, HDIM * CDIM);
    k_zero<<<(2 * GDIM * CDIM + 255) / 256, 256, 0, stream>>>(w.p, 2 * GDIM * CDIM);

    if (combined) {
        pipeline(w, x1, x2, ei1, ei2, batch1, batch2, att_src, att_dst, conv_b,
                 mlp_b1, mlp_b2, w.p, (size_t)GDIM * CDIM, 2, stream);
    } else {
        pipeline(w, x1, x1, ei1, ei1, batch1, batch1, att_src, att_dst, conv_b,
                 mlp_b1, mlp_b2, w.p, 0, 1, stream);
        pipeline(w, x2, x2, ei2, ei2, batch2, batch2, att_src, att_dst, conv_b,
                 mlp_b1, mlp_b2, w.p + GDIM * CDIM, 0, 1, stream);
    }

    k_final<<<CDIM, 64, 0, stream>>>(w.p, out);
}

// Round 6
// 441.529 us; speedup vs baseline: 2.0722x; 1.1324x over previous
//
#include <hip/hip_runtime.h>
#include <cstdint>
#include <cstddef>

#define NNODES 50000
#define NEDGES 500000
#define NTOT (NEDGES + NNODES)
#define HDIM 128
#define CDIM 64
#define GDIM 64

typedef __bf16 bf16x8 __attribute__((ext_vector_type(8)));
typedef __bf16 bf16x2 __attribute__((ext_vector_type(2)));
typedef float f32x4 __attribute__((ext_vector_type(4)));

// ================= setup: weight casts + Wa vectors + zero p =================
// Wa layout: [layer][type(src,dst)][128] f32

__global__ __launch_bounds__(256) void k_setup(const float* __restrict__ convW,
                                               const float* __restrict__ w1,
                                               const float* __restrict__ w2,
                                               const float* __restrict__ a_s,
                                               const float* __restrict__ a_d,
                                               __bf16* __restrict__ WtC,
                                               __bf16* __restrict__ Wt1,
                                               __bf16* __restrict__ Wt2,
                                               float* __restrict__ Wa,
                                               float* __restrict__ p) {
    int b = blockIdx.x, tid = threadIdx.x;
    if (b < 128) {
        int i = b * 256 + tid;  // 32768 convW elems
        int mat = i >> 14, rem = i & 16383;
        int k = rem >> 7, n = rem & 127;
        WtC[mat * 16384 + n * 128 + k] = (__bf16)convW[i];
    } else if (b < 192) {
        int i = (b - 128) * 256 + tid;  // 16384 w1 elems
        int k = i >> 7, n = i & 127;
        Wt1[n * 128 + k] = (__bf16)w1[i];
    } else if (b < 224) {
        int i = (b - 192) * 256 + tid;  // 8192 w2 elems
        int k = i >> 6, n = i & 63;
        Wt2[n * 128 + k] = (__bf16)w2[i];
    } else if (b == 224) {
        for (int o = tid; o < 512; o += 256) {
            int l = o >> 8, r = o & 255;
            int type = r >> 7, k = r & 127;
            const float* a = (type ? a_d : a_s) + l * 128;
            const float* Wrow = convW + l * 16384 + k * 128;
            float s = 0.f;
            for (int j = 0; j < 128; j++) s += Wrow[j] * a[j];
            Wa[o] = s;
        }
    } else {
        for (int i = tid; i < 2 * GDIM * CDIM; i += 256) p[i] = 0.f;
    }
}

// ================= CSR build (y = branch) =================

__global__ void k_hist(const int* __restrict__ ei0, const int* __restrict__ ei1,
                       int* __restrict__ degB, size_t sN, int e) {
    int i = blockIdx.x * 256 + threadIdx.x;
    const int* dst = (blockIdx.y ? ei1 : ei0) + NEDGES;
    int* deg = degB + blockIdx.y * sN;
    if (i < e) atomicAdd(&deg[dst[i]], 1);
}

__device__ inline int block_scan_incl(int v, int* lds) {
    int lane = threadIdx.x & 63, wid = threadIdx.x >> 6;
#pragma unroll
    for (int off = 1; off < 64; off <<= 1) {
        int nv = __shfl_up(v, off);
        if (lane >= off) v += nv;
    }
    if (lane == 63) lds[wid] = v;
    __syncthreads();
    if (wid == 0) {
        int s = (lane < 16) ? lds[lane] : 0;
#pragma unroll
        for (int off = 1; off < 16; off <<= 1) {
            int nv = __shfl_up(s, off);
            if (lane >= off) s += nv;
        }
        if (lane < 16) lds[lane] = s;
    }
    __syncthreads();
    return (wid > 0) ? v + lds[wid - 1] : v;
}

__global__ __launch_bounds__(1024) void k_scan1(const int* __restrict__ degB, int* __restrict__ inclB,
                                                int* __restrict__ bsumsB, size_t sN, int n) {
    __shared__ int lds[16];
    const int* deg = degB + blockIdx.y * sN;
    int* incl = inclB + blockIdx.y * sN;
    int* bsums = bsumsB + blockIdx.y * 64;
    int i = blockIdx.x * 1024 + threadIdx.x;
    int v = (i < n) ? deg[i] : 0;
    int s = block_scan_incl(v, lds);
    if (i < n) incl[i] = s;
    if (threadIdx.x == 1023) bsums[blockIdx.x] = s;
}

__global__ void k_scan2(int* __restrict__ bsumsB, int nb) {
    int* bsums = bsumsB + blockIdx.y * 64;
    int lane = threadIdx.x;
    int v = (lane < nb) ? bsums[lane] : 0;
#pragma unroll
    for (int off = 1; off < 64; off <<= 1) {
        int nv = __shfl_up(v, off);
        if (lane >= off) v += nv;
    }
    if (lane < nb) bsums[lane] = v;
}

// deg counts REAL edges only; self loop accounted via +i. Writes self-loop col.
__global__ __launch_bounds__(1024) void k_scan3(const int* __restrict__ inclB, const int* __restrict__ degB,
                                                const int* __restrict__ bsumsB, int* __restrict__ rpB,
                                                int* __restrict__ curB, int* __restrict__ colB,
                                                size_t sN, size_t sNp1, size_t sE, int n) {
    int i = blockIdx.x * 1024 + threadIdx.x;
    if (i >= n) return;
    const int* incl = inclB + blockIdx.y * sN;
    const int* deg = degB + blockIdx.y * sN;
    const int* bsums = bsumsB + blockIdx.y * 64;
    int* row_ptr = rpB + blockIdx.y * sNp1;
    int* cursor = curB + blockIdx.y * sN;
    int* col = colB + blockIdx.y * sE;
    int off = (blockIdx.x > 0) ? bsums[blockIdx.x - 1] : 0;
    int inc = incl[i] + off;
    int d = deg[i];
    int start = inc - d + i;
    row_ptr[i + 1] = inc + i + 1;
    col[start] = i;          // self loop at segment head
    cursor[i] = start + 1;
    if (i == 0) row_ptr[0] = 0;
}

__global__ void k_scatter_edges(const int* __restrict__ ei0, const int* __restrict__ ei1,
                                int* __restrict__ curB, int* __restrict__ colB,
                                size_t sN, size_t sE, int e) {
    int i = blockIdx.x * 256 + threadIdx.x;
    if (i >= e) return;
    const int* eis = (blockIdx.y ? ei1 : ei0);
    int s = eis[i];
    int d = eis[NEDGES + i];
    int* cursor = curB + blockIdx.y * sN;
    int* col = colB + blockIdx.y * sE;
    int p = atomicAdd(&cursor[d], 1);
    col[p] = s;
}

// ================= MFMA GEMM: [M,128] @ Wt[BN][128] -> [M,BN] bf16 =================
// MODE 0: plain. MODE 1: relu(acc+bias). MODE 2: acc+bias.  AF32: A is f32.
// ALPHA: also emit alpha_s/alpha_d = A_row . Wa{s,d}

template <int BN, int MODE, bool AF32, bool ALPHA>
__global__ __launch_bounds__(256) void k_gemm_mfma(const float* __restrict__ x0,
                                                   const float* __restrict__ x1,
                                                   const __bf16* __restrict__ Ab, size_t As_,
                                                   const __bf16* __restrict__ Wt,
                                                   const float* __restrict__ bias,
                                                   const float* __restrict__ Was,
                                                   const float* __restrict__ Wad,
                                                   float* __restrict__ asB, float* __restrict__ adB,
                                                   size_t aS,
                                                   __bf16* __restrict__ OutB, size_t Os_, int M) {
    constexpr int WAVES_N = (BN == 128) ? 2 : 1;
    constexpr int WAVES_M = 4 / WAVES_N;
    constexpr int WM = 64 / WAVES_M;  // 32 or 16
    constexpr int MF = WM / 16;       // 2 or 1
    constexpr int NF = 4;
    __shared__ __align__(16) unsigned short As[64][136];
    __shared__ __align__(16) unsigned short Bs[BN][136];
    const int tid = threadIdx.x;
    const int lane = tid & 63, w = tid >> 6;
    const int row0 = blockIdx.x * 64;
    __bf16* Out = OutB + blockIdx.y * Os_;

    // stage A (64 rows x 128)
#pragma unroll
    for (int t = 0; t < 4; t++) {
        int ch = t * 256 + tid;
        int r = ch >> 4, cx = ch & 15;
        int grow = row0 + r;
        bf16x8 v = {};
        if (grow < M) {
            if (AF32) {
                const float* Ap = (blockIdx.y ? x1 : x0) + (size_t)grow * 128 + cx * 8;
                float4 f0 = *reinterpret_cast<const float4*>(Ap);
                float4 f1 = *reinterpret_cast<const float4*>(Ap + 4);
                v[0] = (__bf16)f0.x; v[1] = (__bf16)f0.y; v[2] = (__bf16)f0.z; v[3] = (__bf16)f0.w;
                v[4] = (__bf16)f1.x; v[5] = (__bf16)f1.y; v[6] = (__bf16)f1.z; v[7] = (__bf16)f1.w;
            } else {
                v = *reinterpret_cast<const bf16x8*>(Ab + blockIdx.y * As_ + (size_t)grow * 128 + cx * 8);
            }
        }
        *reinterpret_cast<bf16x8*>(&As[r][cx * 8]) = v;
    }
    // stage B
#pragma unroll
    for (int t = 0; t < BN / 16; t++) {
        int ch = t * 256 + tid;
        int r = ch >> 4, cx = ch & 15;
        bf16x8 v = *reinterpret_cast<const bf16x8*>(Wt + (size_t)r * 128 + cx * 8);
        *reinterpret_cast<bf16x8*>(&Bs[r][cx * 8]) = v;
    }
    __syncthreads();

    if (ALPHA) {
        int row = tid >> 2, seg = tid & 3;
        float ss = 0.f, sd = 0.f;
#pragma unroll
        for (int k = 0; k < 32; k++) {
            int kk = seg * 32 + k;
            float a = __int_as_float(((unsigned)As[row][kk]) << 16);
            ss += a * Was[kk];
            sd += a * Wad[kk];
        }
        ss += __shfl_xor(ss, 1); ss += __shfl_xor(ss, 2);
        sd += __shfl_xor(sd, 1); sd += __shfl_xor(sd, 2);
        if (seg == 0) {
            int grow = row0 + row;
            if (grow < M) {
                (asB + blockIdx.y * aS)[grow] = ss;
                (adB + blockIdx.y * aS)[grow] = sd;
            }
        }
    }

    const int wr0 = (w / WAVES_N) * WM;
    const int wc0 = (w % WAVES_N) * 64;
    f32x4 acc[MF][NF] = {};

#pragma unroll
    for (int ks = 0; ks < 4; ks++) {
        const int koff = ks * 32 + (lane >> 4) * 8;
        bf16x8 af[MF], bfr[NF];
#pragma unroll
        for (int mf = 0; mf < MF; mf++)
            af[mf] = *reinterpret_cast<const bf16x8*>(&As[wr0 + mf * 16 + (lane & 15)][koff]);
#pragma unroll
        for (int nf = 0; nf < NF; nf++)
            bfr[nf] = *reinterpret_cast<const bf16x8*>(&Bs[wc0 + nf * 16 + (lane & 15)][koff]);
#pragma unroll
        for (int mf = 0; mf < MF; mf++)
#pragma unroll
            for (int nf = 0; nf < NF; nf++)
                acc[mf][nf] = __builtin_amdgcn_mfma_f32_16x16x32_bf16(af[mf], bfr[nf], acc[mf][nf], 0, 0, 0);
    }

#pragma unroll
    for (int mf = 0; mf < MF; mf++) {
#pragma unroll
        for (int r = 0; r < 4; r++) {
            int row = row0 + wr0 + mf * 16 + (lane >> 4) * 4 + r;
            if (row >= M) continue;
#pragma unroll
            for (int nf = 0; nf < NF; nf++) {
                int colc = wc0 + nf * 16 + (lane & 15);
                float v = acc[mf][nf][r];
                if (MODE == 1) v = fmaxf(v + bias[colc], 0.f);
                if (MODE == 2) v = v + bias[colc];
                Out[(size_t)row * BN + colc] = (__bf16)v;
            }
        }
    }
}

// ================= fused segment-softmax + aggregate + bias + ELU =================
// one wave per dst node; 16 lanes x 16B cover one 256B h row; 4 edges in flight.

__global__ __launch_bounds__(256) void k_gat_agg(const __bf16* __restrict__ hB, size_t hS,
                                                 const float* __restrict__ asB,
                                                 const float* __restrict__ adB, size_t aS,
                                                 const int* __restrict__ rpB, size_t sNp1,
                                                 const int* __restrict__ colB, size_t sE,
                                                 const float* __restrict__ bias,
                                                 __bf16* __restrict__ outB, size_t oS, int n) {
    int node = blockIdx.x * 4 + (threadIdx.x >> 6);
    int lane = threadIdx.x & 63;
    if (node >= n) return;
    const float* alpha_s = asB + blockIdx.y * aS;
    const int* row_ptr = rpB + blockIdx.y * sNp1;
    const int* col = colB + blockIdx.y * sE;
    const bf16x8* h8 = reinterpret_cast<const bf16x8*>(hB + blockIdx.y * hS);
    float ad = (adB + blockIdx.y * aS)[node];
    int beg = row_ptr[node], end = row_ptr[node + 1];
    int deg = end - beg;
    int sub = lane >> 4, fo = lane & 15;

    float acc[8] = {0.f, 0.f, 0.f, 0.f, 0.f, 0.f, 0.f, 0.f};

    if (deg <= 64) {
        bool v = lane < deg;
        int c = 0;
        float e = -1e30f;
        if (v) {
            c = col[beg + lane];
            e = alpha_s[c] + ad;
            e = (e > 0.f) ? e : 0.2f * e;
        }
        float m = e;
#pragma unroll
        for (int off = 32; off; off >>= 1) m = fmaxf(m, __shfl_xor(m, off));
        float ex = v ? __expf(e - m) : 0.f;
        float den = ex;
#pragma unroll
        for (int off = 32; off; off >>= 1) den += __shfl_xor(den, off);
        float wn = ex / den;

        int nIter = (deg + 3) >> 2;
        int k = sub;
        for (int t = 0; t < nIter; t += 2) {
            int k1 = k & 63, k2 = (k + 4) & 63;
            int c1 = __shfl(c, k1); float w1 = __shfl(wn, k1);
            int c2 = __shfl(c, k2); float w2 = __shfl(wn, k2);
            bool v1 = k < deg, v2 = (k + 4) < deg;
            w1 = v1 ? w1 : 0.f; c1 = v1 ? c1 : 0;
            w2 = v2 ? w2 : 0.f; c2 = v2 ? c2 : 0;
            bf16x8 h1 = h8[(size_t)c1 * 16 + fo];
            bf16x8 h2 = h8[(size_t)c2 * 16 + fo];
#pragma unroll
            for (int q = 0; q < 8; q++) acc[q] += w1 * (float)h1[q] + w2 * (float)h2[q];
            k += 8;
        }
    } else {
        float m = -1e30f;
        for (int i = beg + lane; i < end; i += 64) {
            float e = alpha_s[col[i]] + ad;
            e = (e > 0.f) ? e : 0.2f * e;
            m = fmaxf(m, e);
        }
#pragma unroll
        for (int off = 32; off; off >>= 1) m = fmaxf(m, __shfl_xor(m, off));
        float den = 0.f;
        for (int i = beg + lane; i < end; i += 64) {
            float e = alpha_s[col[i]] + ad;
            e = (e > 0.f) ? e : 0.2f * e;
            den += __expf(e - m);
        }
#pragma unroll
        for (int off = 32; off; off >>= 1) den += __shfl_xor(den, off);
        float rinv = 1.f / den;
        for (int i = beg + sub; i < end; i += 4) {
            int cc = col[i];
            float e = alpha_s[cc] + ad;
            e = (e > 0.f) ? e : 0.2f * e;
            float wv = __expf(e - m) * rinv;
            bf16x8 hv = h8[(size_t)cc * 16 + fo];
#pragma unroll
            for (int q = 0; q < 8; q++) acc[q] += wv * (float)hv[q];
        }
    }

#pragma unroll
    for (int q = 0; q < 8; q++) {
        acc[q] += __shfl_xor(acc[q], 16);
        acc[q] += __shfl_xor(acc[q], 32);
    }
    if (sub == 0) {
        float4 b0 = reinterpret_cast<const float4*>(bias)[fo * 2];
        float4 b1 = reinterpret_cast<const float4*>(bias)[fo * 2 + 1];
        float vb[8] = {acc[0] + b0.x, acc[1] + b0.y, acc[2] + b0.z, acc[3] + b0.w,
                       acc[4] + b1.x, acc[5] + b1.y, acc[6] + b1.z, acc[7] + b1.w};
        bf16x8 o;
#pragma unroll
        for (int q = 0; q < 8; q++) {
            float x = vb[q];
            x = (x > 0.f) ? x : __expf(x) - 1.f;
            o[q] = (__bf16)x;
        }
        reinterpret_cast<bf16x8*>(outB + blockIdx.y * oS)[(size_t)node * 16 + fo] = o;
    }
}

// ================= pooling (batch sorted), U bf16 [N,64] =================

__global__ __launch_bounds__(64) void k_pool(const __bf16* __restrict__ uB, size_t uS,
                                             const int* __restrict__ bat0, const int* __restrict__ bat1,
                                             float* __restrict__ pB, size_t pS, int n) {
    int lane = threadIdx.x;
    const __bf16* u = uB + blockIdx.y * uS;
    const int* batch = blockIdx.y ? bat1 : bat0;
    float* p = pB + blockIdx.y * pS;
    int base = blockIdx.x * 64;
    int endn = min(base + 64, n);
    float acc = 0.f;
    int cur = -1;
    for (int nn = base; nn < endn; ++nn) {
        int g = batch[nn];
        if (g != cur) {
            if (cur >= 0) atomicAdd(&p[cur * CDIM + lane], acc);
            acc = 0.f;
            cur = g;
        }
        acc += (float)u[(size_t)nn * CDIM + lane];
    }
    if (cur >= 0) atomicAdd(&p[cur * CDIM + lane], acc);
}

// ================= final p1^T @ p2 =================

__global__ __launch_bounds__(64) void k_final(const float* __restrict__ p, float* __restrict__ out) {
    int i = blockIdx.x;
    int j = threadIdx.x;
    const float* p1 = p;
    const float* p2 = p + GDIM * CDIM;
    float s = 0.f;
    for (int g = 0; g < GDIM; ++g) s += p1[g * CDIM + i] * p2[g * CDIM + j];
    out[i * CDIM + j] = s;
}

// ================= host side =================

static inline size_t align_up(size_t x, size_t a) { return (x + a - 1) & ~(a - 1); }

struct Ws {
    __bf16 *Hb, *Yb, *U;
    __bf16 *WtC, *Wt1, *Wt2;
    float *alpha_s, *alpha_d, *Wa, *p;
    int *deg, *incl, *row_ptr, *cursor, *bsums, *col;
    size_t sNH, sNC, sN, sNp1, sE;
    size_t need;
};

static Ws carve(void* ws, bool combined) {
    char* p = (char*)ws;
    size_t off = 0;
    Ws w;
    int nb = combined ? 2 : 1;
    auto take = [&](size_t bytes) {
        char* r = p + off;
        off = align_up(off + bytes, 256);
        return r;
    };
    w.Hb = (__bf16*)take((size_t)nb * NNODES * HDIM * 2);
    w.Yb = (__bf16*)take((size_t)nb * NNODES * HDIM * 2);
    w.U = (__bf16*)take((size_t)nb * NNODES * CDIM * 2);
    w.alpha_s = (float*)take((size_t)nb * NNODES * 4);
    w.alpha_d = (float*)take((size_t)nb * NNODES * 4);
    w.col = (int*)take((size_t)nb * NTOT * 4);
    w.deg = (int*)take((size_t)nb * NNODES * 4);
    w.incl = (int*)take((size_t)nb * NNODES * 4);
    w.row_ptr = (int*)take((size_t)nb * (NNODES + 1) * 4);
    w.cursor = (int*)take((size_t)nb * NNODES * 4);
    w.bsums = (int*)take((size_t)2 * 64 * 4);
    w.WtC = (__bf16*)take((size_t)2 * HDIM * HDIM * 2);
    w.Wt1 = (__bf16*)take((size_t)HDIM * HDIM * 2);
    w.Wt2 = (__bf16*)take((size_t)HDIM * CDIM * 2);
    w.Wa = (float*)take((size_t)512 * 4);
    w.p = (float*)take((size_t)2 * GDIM * CDIM * 4);
    w.need = off;
    size_t s = combined ? 1 : 0;
    w.sNH = s * (size_t)NNODES * HDIM;
    w.sNC = s * (size_t)NNODES * CDIM;
    w.sN = s * (size_t)NNODES;
    w.sNp1 = s * (size_t)(NNODES + 1);
    w.sE = s * (size_t)NTOT;
    return w;
}

static void pipeline(const Ws& w, const float* xA, const float* xB,
                     const int* eiA, const int* eiB,
                     const int* batA, const int* batB,
                     const float* conv_b, const float* b1, const float* b2,
                     float* pbase, size_t pstride, int yc, hipStream_t stream) {
    const int N = NNODES, E = NEDGES;
    dim3 gE((E + 255) / 256, yc);
    int nb = (N + 1023) / 1024;
    dim3 gS(nb, yc), g1(1, yc);
    dim3 gW((N + 3) / 4, yc);
    dim3 gG((N + 63) / 64, yc);
    dim3 gP((N + 63) / 64, yc);

    hipMemsetAsync(w.deg, 0, (size_t)yc * N * 4, stream);
    k_hist<<<gE, 256, 0, stream>>>(eiA, eiB, w.deg, w.sN, E);
    k_scan1<<<gS, 1024, 0, stream>>>(w.deg, w.incl, w.bsums, w.sN, N);
    k_scan2<<<g1, 64, 0, stream>>>(w.bsums, nb);
    k_scan3<<<gS, 1024, 0, stream>>>(w.incl, w.deg, w.bsums, w.row_ptr, w.cursor, w.col,
                                     w.sN, w.sNp1, w.sE, N);
    k_scatter_edges<<<gE, 256, 0, stream>>>(eiA, eiB, w.cursor, w.col, w.sN, w.sE, E);

    // conv layer 0 (A = x f32, fused cast + fused alpha)
    k_gemm_mfma<HDIM, 0, true, true><<<gG, 256, 0, stream>>>(
        xA, xB, nullptr, 0, w.WtC, nullptr, w.Wa, w.Wa + 128,
        w.alpha_s, w.alpha_d, w.sN, w.Hb, w.sNH, N);
    k_gat_agg<<<gW, 256, 0, stream>>>(w.Hb, w.sNH, w.alpha_s, w.alpha_d, w.sN,
                                      w.row_ptr, w.sNp1, w.col, w.sE, conv_b, w.Yb, w.sNH, N);
    // conv layer 1
    k_gemm_mfma<HDIM, 0, false, true><<<gG, 256, 0, stream>>>(
        nullptr, nullptr, w.Yb, w.sNH, w.WtC + HDIM * HDIM, nullptr, w.Wa + 256, w.Wa + 384,
        w.alpha_s, w.alpha_d, w.sN, w.Hb, w.sNH, N);
    k_gat_agg<<<gW, 256, 0, stream>>>(w.Hb, w.sNH, w.alpha_s, w.alpha_d, w.sN,
                                      w.row_ptr, w.sNp1, w.col, w.sE, conv_b + HDIM, w.Yb, w.sNH, N);
    // MLP
    k_gemm_mfma<HDIM, 1, false, false><<<gG, 256, 0, stream>>>(
        nullptr, nullptr, w.Yb, w.sNH, w.Wt1, b1, nullptr, nullptr,
        nullptr, nullptr, 0, w.Hb, w.sNH, N);
    k_gemm_mfma<CDIM, 2, false, false><<<gG, 256, 0, stream>>>(
        nullptr, nullptr, w.Hb, w.sNH, w.Wt2, b2, nullptr, nullptr,
        nullptr, nullptr, 0, w.U, w.sNC, N);

    k_pool<<<gP, 64, 0, stream>>>(w.U, w.sNC, batA, batB, pbase, pstride, N);
}

extern "C" void kernel_launch(void* const* d_in, const int* in_sizes, int n_in, void* d_out,
                              int out_size, void* d_ws, size_t ws_size, hipStream_t stream) {
    const float* x1      = (const float*)d_in[0];
    const float* x2      = (const float*)d_in[1];
    const float* convW   = (const float*)d_in[2];
    const float* att_src = (const float*)d_in[3];
    const float* att_dst = (const float*)d_in[4];
    const float* conv_b  = (const float*)d_in[5];
    const float* mlp_w1  = (const float*)d_in[6];
    const float* mlp_b1  = (const float*)d_in[7];
    const float* mlp_w2  = (const float*)d_in[8];
    const float* mlp_b2  = (const float*)d_in[9];
    const int* ei1       = (const int*)d_in[10];
    const int* batch1    = (const int*)d_in[11];
    const int* ei2       = (const int*)d_in[12];
    const int* batch2    = (const int*)d_in[13];
    float* out = (float*)d_out;

    Ws wc = carve(d_ws, true);
    bool combined = ws_size >= wc.need;
    Ws w = combined ? wc : carve(d_ws, false);

    k_setup<<<226, 256, 0, stream>>>(convW, mlp_w1, mlp_w2, att_src, att_dst,
                                     w.WtC, w.Wt1, w.Wt2, w.Wa, w.p);

    if (combined) {
        pipeline(w, x1, x2, ei1, ei2, batch1, batch2, conv_b,
                 mlp_b1, mlp_b2, w.p, (size_t)GDIM * CDIM, 2, stream);
    } else {
        pipeline(w, x1, x1, ei1, ei1, batch1, batch1, conv_b,
                 mlp_b1, mlp_b2, w.p, 0, 1, stream);
        pipeline(w, x2, x2, ei2, ei2, batch2, batch2, conv_b,
                 mlp_b1, mlp_b2, w.p + GDIM * CDIM, 0, 1, stream);
    }

    k_final<<<CDIM, 64, 0, stream>>>(w.p, out);
}

// Round 7
// 374.932 us; speedup vs baseline: 2.4403x; 1.1776x over previous
//
#include <hip/hip_runtime.h>
#include <cstdint>
#include <cstddef>

#define NNODES 50000
#define NEDGES 500000
#define NTOT (NEDGES + NNODES)
#define HDIM 128
#define CDIM 64
#define GDIM 64
#define NB 250      // buckets
#define NPB 200     // nodes per bucket
#define CHUNK 2048  // edges per partition block
#define NCHB ((NEDGES + CHUNK - 1) / CHUNK)

typedef __bf16 bf16x8 __attribute__((ext_vector_type(8)));
typedef float f32x4 __attribute__((ext_vector_type(4)));

// ================= setup: weight casts + Wa vectors + zero p =================

__global__ __launch_bounds__(256) void k_setup(const float* __restrict__ convW,
                                               const float* __restrict__ w1,
                                               const float* __restrict__ w2,
                                               const float* __restrict__ a_s,
                                               const float* __restrict__ a_d,
                                               __bf16* __restrict__ WtC,
                                               __bf16* __restrict__ Wt1,
                                               __bf16* __restrict__ Wt2,
                                               float* __restrict__ Wa,
                                               float* __restrict__ p) {
    int b = blockIdx.x, tid = threadIdx.x;
    if (b < 128) {
        int i = b * 256 + tid;
        int mat = i >> 14, rem = i & 16383;
        int k = rem >> 7, n = rem & 127;
        WtC[mat * 16384 + n * 128 + k] = (__bf16)convW[i];
    } else if (b < 192) {
        int i = (b - 128) * 256 + tid;
        int k = i >> 7, n = i & 127;
        Wt1[n * 128 + k] = (__bf16)w1[i];
    } else if (b < 224) {
        int i = (b - 192) * 256 + tid;
        int k = i >> 6, n = i & 63;
        Wt2[n * 128 + k] = (__bf16)w2[i];
    } else if (b == 224) {
        for (int o = tid; o < 512; o += 256) {
            int l = o >> 8, r = o & 255;
            int type = r >> 7, k = r & 127;
            const float* a = (type ? a_d : a_s) + l * 128;
            const float* Wrow = convW + l * 16384 + k * 128;
            float s = 0.f;
            for (int j = 0; j < 128; j++) s += Wrow[j] * a[j];
            Wa[o] = s;
        }
    } else {
        for (int i = tid; i < 2 * GDIM * CDIM; i += 256) p[i] = 0.f;
    }
}

// ================= CSR build via 2-level bucket sort (y = branch) =================

__global__ __launch_bounds__(256) void k_bhist(const int* __restrict__ ei0,
                                               const int* __restrict__ ei1,
                                               int* __restrict__ bcntB, int e) {
    __shared__ int h[NB];
    const int* dst = (blockIdx.y ? ei1 : ei0) + NEDGES;
    int* bcnt = bcntB + blockIdx.y * NB;
    for (int t = threadIdx.x; t < NB; t += 256) h[t] = 0;
    __syncthreads();
    int base = blockIdx.x * CHUNK;
    int lim = min(base + CHUNK, e);
    for (int i = base + threadIdx.x; i < lim; i += 256) atomicAdd(&h[dst[i] / NPB], 1);
    __syncthreads();
    for (int t = threadIdx.x; t < NB; t += 256)
        if (h[t]) atomicAdd(&bcnt[t], h[t]);
}

__global__ __launch_bounds__(256) void k_bscan(const int* __restrict__ bcntB,
                                               int* __restrict__ boffB,
                                               int* __restrict__ bcurB) {
    __shared__ int s[256];
    int t = threadIdx.x;
    const int* bcnt = bcntB + blockIdx.y * NB;
    int* boff = boffB + blockIdx.y * (NB + 1);
    int* bcur = bcurB + blockIdx.y * NB;
    int v = (t < NB) ? bcnt[t] : 0;
    s[t] = v;
    __syncthreads();
    for (int off = 1; off < 256; off <<= 1) {
        int x = (t >= off) ? s[t - off] : 0;
        __syncthreads();
        s[t] += x;
        __syncthreads();
    }
    if (t < NB) {
        boff[t + 1] = s[t];
        bcur[t] = s[t] - v;  // exclusive
        if (t == 0) boff[0] = 0;
    }
}

__global__ __launch_bounds__(256) void k_part(const int* __restrict__ ei0,
                                              const int* __restrict__ ei1,
                                              int* __restrict__ bcurB,
                                              int2* __restrict__ partB, int e) {
    __shared__ int cnt[NB], boffL[NB], gbase[NB], cur2[NB];
    __shared__ int tmp[256];
    __shared__ int2 staged[CHUNK];
    const int* eis = blockIdx.y ? ei1 : ei0;
    int* bcur = bcurB + blockIdx.y * NB;
    int2* part = partB + blockIdx.y * (size_t)NEDGES;
    int t = threadIdx.x;
    for (int i = t; i < NB; i += 256) { cnt[i] = 0; cur2[i] = 0; }
    __syncthreads();
    int base = blockIdx.x * CHUNK;
    int lim = min(base + CHUNK, e);
    int nloc = lim - base;

    int s_[8], d_[8], b_[8];
    bool v_[8];
#pragma unroll
    for (int k = 0; k < 8; k++) {
        int i = base + k * 256 + t;
        v_[k] = i < lim;
        s_[k] = 0; d_[k] = 0; b_[k] = 0;
        if (v_[k]) {
            s_[k] = eis[i];
            d_[k] = eis[NEDGES + i];
            b_[k] = d_[k] / NPB;
            atomicAdd(&cnt[b_[k]], 1);
        }
    }
    __syncthreads();
    tmp[t] = (t < NB) ? cnt[t] : 0;
    __syncthreads();
    for (int off = 1; off < 256; off <<= 1) {
        int x = (t >= off) ? tmp[t - off] : 0;
        __syncthreads();
        tmp[t] += x;
        __syncthreads();
    }
    if (t < NB) boffL[t] = tmp[t] - cnt[t];
    __syncthreads();
    if (t < NB) {
        int c = cnt[t];
        gbase[t] = c ? atomicAdd(&bcur[t], c) : 0;
    }
    __syncthreads();
#pragma unroll
    for (int k = 0; k < 8; k++) {
        if (v_[k]) {
            int pos = atomicAdd(&cur2[b_[k]], 1);
            staged[boffL[b_[k]] + pos] = make_int2(s_[k], d_[k]);
        }
    }
    __syncthreads();
    for (int i = t; i < nloc; i += 256) {
        int2 r = staged[i];
        int b = r.y / NPB;
        part[gbase[b] + (i - boffL[b])] = r;
    }
}

__global__ __launch_bounds__(256) void k_bdeg(const int2* __restrict__ partB,
                                              const int* __restrict__ boffB,
                                              int* __restrict__ degB, size_t sN) {
    __shared__ int h[NPB];
    int b = blockIdx.x;
    const int* boff = boffB + blockIdx.y * (NB + 1);
    const int2* part = partB + blockIdx.y * (size_t)NEDGES;
    int* deg = degB + blockIdx.y * sN;
    int t = threadIdx.x;
    if (t < NPB) h[t] = 0;
    __syncthreads();
    int beg = boff[b], end = boff[b + 1];
    int n0 = b * NPB;
    for (int i = beg + t; i < end; i += 256) atomicAdd(&h[part[i].y - n0], 1);
    __syncthreads();
    if (t < NPB) deg[n0 + t] = h[t];
}

__device__ inline int block_scan_incl(int v, int* lds) {
    int lane = threadIdx.x & 63, wid = threadIdx.x >> 6;
#pragma unroll
    for (int off = 1; off < 64; off <<= 1) {
        int nv = __shfl_up(v, off);
        if (lane >= off) v += nv;
    }
    if (lane == 63) lds[wid] = v;
    __syncthreads();
    if (wid == 0) {
        int s = (lane < 16) ? lds[lane] : 0;
#pragma unroll
        for (int off = 1; off < 16; off <<= 1) {
            int nv = __shfl_up(s, off);
            if (lane >= off) s += nv;
        }
        if (lane < 16) lds[lane] = s;
    }
    __syncthreads();
    return (wid > 0) ? v + lds[wid - 1] : v;
}

__global__ __launch_bounds__(1024) void k_scan1(const int* __restrict__ degB, int* __restrict__ inclB,
                                                int* __restrict__ bsumsB, size_t sN, int n) {
    __shared__ int lds[16];
    const int* deg = degB + blockIdx.y * sN;
    int* incl = inclB + blockIdx.y * sN;
    int* bsums = bsumsB + blockIdx.y * 64;
    int i = blockIdx.x * 1024 + threadIdx.x;
    int v = (i < n) ? deg[i] : 0;
    int s = block_scan_incl(v, lds);
    if (i < n) incl[i] = s;
    if (threadIdx.x == 1023) bsums[blockIdx.x] = s;
}

__global__ void k_scan2(int* __restrict__ bsumsB, int nb) {
    int* bsums = bsumsB + blockIdx.y * 64;
    int lane = threadIdx.x;
    int v = (lane < nb) ? bsums[lane] : 0;
#pragma unroll
    for (int off = 1; off < 64; off <<= 1) {
        int nv = __shfl_up(v, off);
        if (lane >= off) v += nv;
    }
    if (lane < nb) bsums[lane] = v;
}

// deg counts REAL edges; self loop accounted via +i.
__global__ __launch_bounds__(1024) void k_scan3(const int* __restrict__ inclB,
                                                const int* __restrict__ bsumsB, int* __restrict__ rpB,
                                                size_t sN, size_t sNp1, int n) {
    int i = blockIdx.x * 1024 + threadIdx.x;
    if (i >= n) return;
    const int* incl = inclB + blockIdx.y * sN;
    const int* bsums = bsumsB + blockIdx.y * 64;
    int* row_ptr = rpB + blockIdx.y * sNp1;
    int off = (blockIdx.x > 0) ? bsums[blockIdx.x - 1] : 0;
    row_ptr[i + 1] = incl[i] + off + i + 1;
    if (i == 0) row_ptr[0] = 0;
}

__global__ __launch_bounds__(256) void k_place(const int2* __restrict__ partB,
                                               const int* __restrict__ boffB,
                                               const int* __restrict__ rpB, size_t sNp1,
                                               int* __restrict__ colB, size_t sE) {
    __shared__ int cur[NPB];
    int b = blockIdx.x;
    const int* boff = boffB + blockIdx.y * (NB + 1);
    const int2* part = partB + blockIdx.y * (size_t)NEDGES;
    const int* row_ptr = rpB + blockIdx.y * sNp1;
    int* col = colB + blockIdx.y * sE;
    int t = threadIdx.x;
    int n0 = b * NPB;
    if (t < NPB) {
        int rp = row_ptr[n0 + t];
        cur[t] = rp + 1;
        col[rp] = n0 + t;  // self loop at segment head
    }
    __syncthreads();
    int beg = boff[b], end = boff[b + 1];
    for (int i = beg + t; i < end; i += 256) {
        int2 r = part[i];
        int p = atomicAdd(&cur[r.y - n0], 1);
        col[p] = r.x;
    }
}

// ================= MFMA GEMM: [M,128] @ Wt[BN][128] -> [M,BN] bf16 =================
// MODE 0: plain. MODE 1: relu(acc+bias). MODE 2: acc+bias.  AF32: A is f32.
// ALPHA: also emit alpha_s/alpha_d = A_row . Wa{s,d}

template <int BN, int MODE, bool AF32, bool ALPHA>
__global__ __launch_bounds__(256) void k_gemm_mfma(const float* __restrict__ x0,
                                                   const float* __restrict__ x1,
                                                   const __bf16* __restrict__ Ab, size_t As_,
                                                   const __bf16* __restrict__ Wt,
                                                   const float* __restrict__ bias,
                                                   const float* __restrict__ Was,
                                                   const float* __restrict__ Wad,
                                                   float* __restrict__ asB, float* __restrict__ adB,
                                                   size_t aS,
                                                   __bf16* __restrict__ OutB, size_t Os_, int M) {
    constexpr int WAVES_N = (BN == 128) ? 2 : 1;
    constexpr int WAVES_M = 4 / WAVES_N;
    constexpr int WM = 64 / WAVES_M;
    constexpr int MF = WM / 16;
    constexpr int NF = 4;
    __shared__ __align__(16) unsigned short As[64][136];
    __shared__ __align__(16) unsigned short Bs[BN][136];
    const int tid = threadIdx.x;
    const int lane = tid & 63, w = tid >> 6;
    const int row0 = blockIdx.x * 64;
    __bf16* Out = OutB + blockIdx.y * Os_;

#pragma unroll
    for (int t = 0; t < 4; t++) {
        int ch = t * 256 + tid;
        int r = ch >> 4, cx = ch & 15;
        int grow = row0 + r;
        bf16x8 v = {};
        if (grow < M) {
            if (AF32) {
                const float* Ap = (blockIdx.y ? x1 : x0) + (size_t)grow * 128 + cx * 8;
                float4 f0 = *reinterpret_cast<const float4*>(Ap);
                float4 f1 = *reinterpret_cast<const float4*>(Ap + 4);
                v[0] = (__bf16)f0.x; v[1] = (__bf16)f0.y; v[2] = (__bf16)f0.z; v[3] = (__bf16)f0.w;
                v[4] = (__bf16)f1.x; v[5] = (__bf16)f1.y; v[6] = (__bf16)f1.z; v[7] = (__bf16)f1.w;
            } else {
                v = *reinterpret_cast<const bf16x8*>(Ab + blockIdx.y * As_ + (size_t)grow * 128 + cx * 8);
            }
        }
        *reinterpret_cast<bf16x8*>(&As[r][cx * 8]) = v;
    }
#pragma unroll
    for (int t = 0; t < BN / 16; t++) {
        int ch = t * 256 + tid;
        int r = ch >> 4, cx = ch & 15;
        bf16x8 v = *reinterpret_cast<const bf16x8*>(Wt + (size_t)r * 128 + cx * 8);
        *reinterpret_cast<bf16x8*>(&Bs[r][cx * 8]) = v;
    }
    __syncthreads();

    if (ALPHA) {
        int row = tid >> 2, seg = tid & 3;
        float ss = 0.f, sd = 0.f;
#pragma unroll
        for (int k = 0; k < 32; k++) {
            int kk = seg * 32 + k;
            float a = __int_as_float(((unsigned)As[row][kk]) << 16);
            ss += a * Was[kk];
            sd += a * Wad[kk];
        }
        ss += __shfl_xor(ss, 1); ss += __shfl_xor(ss, 2);
        sd += __shfl_xor(sd, 1); sd += __shfl_xor(sd, 2);
        if (seg == 0) {
            int grow = row0 + row;
            if (grow < M) {
                (asB + blockIdx.y * aS)[grow] = ss;
                (adB + blockIdx.y * aS)[grow] = sd;
            }
        }
    }

    const int wr0 = (w / WAVES_N) * WM;
    const int wc0 = (w % WAVES_N) * 64;
    f32x4 acc[MF][NF] = {};

#pragma unroll
    for (int ks = 0; ks < 4; ks++) {
        const int koff = ks * 32 + (lane >> 4) * 8;
        bf16x8 af[MF], bfr[NF];
#pragma unroll
        for (int mf = 0; mf < MF; mf++)
            af[mf] = *reinterpret_cast<const bf16x8*>(&As[wr0 + mf * 16 + (lane & 15)][koff]);
#pragma unroll
        for (int nf = 0; nf < NF; nf++)
            bfr[nf] = *reinterpret_cast<const bf16x8*>(&Bs[wc0 + nf * 16 + (lane & 15)][koff]);
#pragma unroll
        for (int mf = 0; mf < MF; mf++)
#pragma unroll
            for (int nf = 0; nf < NF; nf++)
                acc[mf][nf] = __builtin_amdgcn_mfma_f32_16x16x32_bf16(af[mf], bfr[nf], acc[mf][nf], 0, 0, 0);
    }

#pragma unroll
    for (int mf = 0; mf < MF; mf++) {
#pragma unroll
        for (int r = 0; r < 4; r++) {
            int row = row0 + wr0 + mf * 16 + (lane >> 4) * 4 + r;
            if (row >= M) continue;
#pragma unroll
            for (int nf = 0; nf < NF; nf++) {
                int colc = wc0 + nf * 16 + (lane & 15);
                float v = acc[mf][nf][r];
                if (MODE == 1) v = fmaxf(v + bias[colc], 0.f);
                if (MODE == 2) v = v + bias[colc];
                Out[(size_t)row * BN + colc] = (__bf16)v;
            }
        }
    }
}

// ================= fused segment-softmax + aggregate + bias + ELU =================

__global__ __launch_bounds__(256) void k_gat_agg(const __bf16* __restrict__ hB, size_t hS,
                                                 const float* __restrict__ asB,
                                                 const float* __restrict__ adB, size_t aS,
                                                 const int* __restrict__ rpB, size_t sNp1,
                                                 const int* __restrict__ colB, size_t sE,
                                                 const float* __restrict__ bias,
                                                 __bf16* __restrict__ outB, size_t oS, int n) {
    int node = blockIdx.x * 4 + (threadIdx.x >> 6);
    int lane = threadIdx.x & 63;
    if (node >= n) return;
    const float* alpha_s = asB + blockIdx.y * aS;
    const int* row_ptr = rpB + blockIdx.y * sNp1;
    const int* col = colB + blockIdx.y * sE;
    const bf16x8* h8 = reinterpret_cast<const bf16x8*>(hB + blockIdx.y * hS);
    float ad = (adB + blockIdx.y * aS)[node];
    int beg = row_ptr[node], end = row_ptr[node + 1];
    int deg = end - beg;
    int sub = lane >> 4, fo = lane & 15;

    float acc[8] = {0.f, 0.f, 0.f, 0.f, 0.f, 0.f, 0.f, 0.f};

    if (deg <= 64) {
        bool v = lane < deg;
        int c = 0;
        float e = -1e30f;
        if (v) {
            c = col[beg + lane];
            e = alpha_s[c] + ad;
            e = (e > 0.f) ? e : 0.2f * e;
        }
        float m = e;
#pragma unroll
        for (int off = 32; off; off >>= 1) m = fmaxf(m, __shfl_xor(m, off));
        float ex = v ? __expf(e - m) : 0.f;
        float den = ex;
#pragma unroll
        for (int off = 32; off; off >>= 1) den += __shfl_xor(den, off);
        float wn = ex / den;

        int nIter = (deg + 3) >> 2;
        int k = sub;
        for (int t = 0; t < nIter; t += 2) {
            int k1 = k & 63, k2 = (k + 4) & 63;
            int c1 = __shfl(c, k1); float w1 = __shfl(wn, k1);
            int c2 = __shfl(c, k2); float w2 = __shfl(wn, k2);
            bool v1 = k < deg, v2 = (k + 4) < deg;
            w1 = v1 ? w1 : 0.f; c1 = v1 ? c1 : 0;
            w2 = v2 ? w2 : 0.f; c2 = v2 ? c2 : 0;
            bf16x8 h1 = h8[(size_t)c1 * 16 + fo];
            bf16x8 h2 = h8[(size_t)c2 * 16 + fo];
#pragma unroll
            for (int q = 0; q < 8; q++) acc[q] += w1 * (float)h1[q] + w2 * (float)h2[q];
            k += 8;
        }
    } else {
        float m = -1e30f;
        for (int i = beg + lane; i < end; i += 64) {
            float e = alpha_s[col[i]] + ad;
            e = (e > 0.f) ? e : 0.2f * e;
            m = fmaxf(m, e);
        }
#pragma unroll
        for (int off = 32; off; off >>= 1) m = fmaxf(m, __shfl_xor(m, off));
        float den = 0.f;
        for (int i = beg + lane; i < end; i += 64) {
            float e = alpha_s[col[i]] + ad;
            e = (e > 0.f) ? e : 0.2f * e;
            den += __expf(e - m);
        }
#pragma unroll
        for (int off = 32; off; off >>= 1) den += __shfl_xor(den, off);
        float rinv = 1.f / den;
        for (int i = beg + sub; i < end; i += 4) {
            int cc = col[i];
            float e = alpha_s[cc] + ad;
            e = (e > 0.f) ? e : 0.2f * e;
            float wv = __expf(e - m) * rinv;
            bf16x8 hv = h8[(size_t)cc * 16 + fo];
#pragma unroll
            for (int q = 0; q < 8; q++) acc[q] += wv * (float)hv[q];
        }
    }

#pragma unroll
    for (int q = 0; q < 8; q++) {
        acc[q] += __shfl_xor(acc[q], 16);
        acc[q] += __shfl_xor(acc[q], 32);
    }
    if (sub == 0) {
        float4 b0 = reinterpret_cast<const float4*>(bias)[fo * 2];
        float4 b1 = reinterpret_cast<const float4*>(bias)[fo * 2 + 1];
        float vb[8] = {acc[0] + b0.x, acc[1] + b0.y, acc[2] + b0.z, acc[3] + b0.w,
                       acc[4] + b1.x, acc[5] + b1.y, acc[6] + b1.z, acc[7] + b1.w};
        bf16x8 o;
#pragma unroll
        for (int q = 0; q < 8; q++) {
            float x = vb[q];
            x = (x > 0.f) ? x : __expf(x) - 1.f;
            o[q] = (__bf16)x;
        }
        reinterpret_cast<bf16x8*>(outB + blockIdx.y * oS)[(size_t)node * 16 + fo] = o;
    }
}

// ================= pooling (batch sorted), U bf16 [N,64] =================

__global__ __launch_bounds__(64) void k_pool(const __bf16* __restrict__ uB, size_t uS,
                                             const int* __restrict__ bat0, const int* __restrict__ bat1,
                                             float* __restrict__ pB, size_t pS, int n) {
    int lane = threadIdx.x;
    const __bf16* u = uB + blockIdx.y * uS;
    const int* batch = blockIdx.y ? bat1 : bat0;
    float* p = pB + blockIdx.y * pS;
    int base = blockIdx.x * 64;
    int endn = min(base + 64, n);
    float acc = 0.f;
    int cur = -1;
    for (int nn = base; nn < endn; ++nn) {
        int g = batch[nn];
        if (g != cur) {
            if (cur >= 0) atomicAdd(&p[cur * CDIM + lane], acc);
            acc = 0.f;
            cur = g;
        }
        acc += (float)u[(size_t)nn * CDIM + lane];
    }
    if (cur >= 0) atomicAdd(&p[cur * CDIM + lane], acc);
}

// ================= final p1^T @ p2 =================

__global__ __launch_bounds__(64) void k_final(const float* __restrict__ p, float* __restrict__ out) {
    int i = blockIdx.x;
    int j = threadIdx.x;
    const float* p1 = p;
    const float* p2 = p + GDIM * CDIM;
    float s = 0.f;
    for (int g = 0; g < GDIM; ++g) s += p1[g * CDIM + i] * p2[g * CDIM + j];
    out[i * CDIM + j] = s;
}

// ================= host side =================

static inline size_t align_up(size_t x, size_t a) { return (x + a - 1) & ~(a - 1); }

struct Ws {
    __bf16 *Hb, *Yb, *U;
    __bf16 *WtC, *Wt1, *Wt2;
    float *alpha_s, *alpha_d, *Wa, *p;
    int *deg, *incl, *row_ptr, *bsums, *col;
    int *bcnt, *boff, *bcur;
    int2* part;
    size_t sNH, sNC, sN, sNp1, sE;
    size_t need;
};

static Ws carve(void* ws, bool combined) {
    char* p = (char*)ws;
    size_t off = 0;
    Ws w;
    int nb = combined ? 2 : 1;
    auto take = [&](size_t bytes) {
        char* r = p + off;
        off = align_up(off + bytes, 256);
        return r;
    };
    w.Hb = (__bf16*)take((size_t)nb * NNODES * HDIM * 2);
    w.Yb = (__bf16*)take((size_t)nb * NNODES * HDIM * 2);
    w.U = (__bf16*)take((size_t)nb * NNODES * CDIM * 2);
    w.alpha_s = (float*)take((size_t)nb * NNODES * 4);
    w.alpha_d = (float*)take((size_t)nb * NNODES * 4);
    w.col = (int*)take((size_t)nb * NTOT * 4);
    w.part = (int2*)take((size_t)nb * NEDGES * 8);
    w.deg = (int*)take((size_t)nb * NNODES * 4);
    w.incl = (int*)take((size_t)nb * NNODES * 4);
    w.row_ptr = (int*)take((size_t)nb * (NNODES + 1) * 4);
    w.bsums = (int*)take((size_t)2 * 64 * 4);
    w.bcnt = (int*)take((size_t)2 * NB * 4);
    w.boff = (int*)take((size_t)2 * (NB + 1) * 4);
    w.bcur = (int*)take((size_t)2 * NB * 4);
    w.WtC = (__bf16*)take((size_t)2 * HDIM * HDIM * 2);
    w.Wt1 = (__bf16*)take((size_t)HDIM * HDIM * 2);
    w.Wt2 = (__bf16*)take((size_t)HDIM * CDIM * 2);
    w.Wa = (float*)take((size_t)512 * 4);
    w.p = (float*)take((size_t)2 * GDIM * CDIM * 4);
    w.need = off;
    size_t s = combined ? 1 : 0;
    w.sNH = s * (size_t)NNODES * HDIM;
    w.sNC = s * (size_t)NNODES * CDIM;
    w.sN = s * (size_t)NNODES;
    w.sNp1 = s * (size_t)(NNODES + 1);
    w.sE = s * (size_t)NTOT;
    return w;
}

static void pipeline(const Ws& w, const float* xA, const float* xB,
                     const int* eiA, const int* eiB,
                     const int* batA, const int* batB,
                     const float* conv_b, const float* b1, const float* b2,
                     float* pbase, size_t pstride, int yc, hipStream_t stream) {
    const int N = NNODES, E = NEDGES;
    int nb = (N + 1023) / 1024;
    dim3 gC(NCHB, yc), gB(NB, yc), g1(1, yc), gS(nb, yc);
    dim3 gW((N + 3) / 4, yc);
    dim3 gG((N + 63) / 64, yc);
    dim3 gP((N + 63) / 64, yc);

    // ---- CSR build (bucketed, write-local) ----
    hipMemsetAsync(w.bcnt, 0, (size_t)yc * NB * 4, stream);
    k_bhist<<<gC, 256, 0, stream>>>(eiA, eiB, w.bcnt, E);
    k_bscan<<<g1, 256, 0, stream>>>(w.bcnt, w.boff, w.bcur);
    k_part<<<gC, 256, 0, stream>>>(eiA, eiB, w.bcur, w.part, E);
    k_bdeg<<<gB, 256, 0, stream>>>(w.part, w.boff, w.deg, w.sN);
    k_scan1<<<gS, 1024, 0, stream>>>(w.deg, w.incl, w.bsums, w.sN, N);
    k_scan2<<<g1, 64, 0, stream>>>(w.bsums, nb);
    k_scan3<<<gS, 1024, 0, stream>>>(w.incl, w.bsums, w.row_ptr, w.sN, w.sNp1, N);
    k_place<<<gB, 256, 0, stream>>>(w.part, w.boff, w.row_ptr, w.sNp1, w.col, w.sE);

    // ---- conv layer 0 (A = x f32, fused cast + fused alpha) ----
    k_gemm_mfma<HDIM, 0, true, true><<<gG, 256, 0, stream>>>(
        xA, xB, nullptr, 0, w.WtC, nullptr, w.Wa, w.Wa + 128,
        w.alpha_s, w.alpha_d, w.sN, w.Hb, w.sNH, N);
    k_gat_agg<<<gW, 256, 0, stream>>>(w.Hb, w.sNH, w.alpha_s, w.alpha_d, w.sN,
                                      w.row_ptr, w.sNp1, w.col, w.sE, conv_b, w.Yb, w.sNH, N);
    // ---- conv layer 1 ----
    k_gemm_mfma<HDIM, 0, false, true><<<gG, 256, 0, stream>>>(
        nullptr, nullptr, w.Yb, w.sNH, w.WtC + HDIM * HDIM, nullptr, w.Wa + 256, w.Wa + 384,
        w.alpha_s, w.alpha_d, w.sN, w.Hb, w.sNH, N);
    k_gat_agg<<<gW, 256, 0, stream>>>(w.Hb, w.sNH, w.alpha_s, w.alpha_d, w.sN,
                                      w.row_ptr, w.sNp1, w.col, w.sE, conv_b + HDIM, w.Yb, w.sNH, N);
    // ---- MLP ----
    k_gemm_mfma<HDIM, 1, false, false><<<gG, 256, 0, stream>>>(
        nullptr, nullptr, w.Yb, w.sNH, w.Wt1, b1, nullptr, nullptr,
        nullptr, nullptr, 0, w.Hb, w.sNH, N);
    k_gemm_mfma<CDIM, 2, false, false><<<gG, 256, 0, stream>>>(
        nullptr, nullptr, w.Hb, w.sNH, w.Wt2, b2, nullptr, nullptr,
        nullptr, nullptr, 0, w.U, w.sNC, N);

    k_pool<<<gP, 64, 0, stream>>>(w.U, w.sNC, batA, batB, pbase, pstride, N);
}

extern "C" void kernel_launch(void* const* d_in, const int* in_sizes, int n_in, void* d_out,
                              int out_size, void* d_ws, size_t ws_size, hipStream_t stream) {
    const float* x1      = (const float*)d_in[0];
    const float* x2      = (const float*)d_in[1];
    const float* convW   = (const float*)d_in[2];
    const float* att_src = (const float*)d_in[3];
    const float* att_dst = (const float*)d_in[4];
    const float* conv_b  = (const float*)d_in[5];
    const float* mlp_w1  = (const float*)d_in[6];
    const float* mlp_b1  = (const float*)d_in[7];
    const float* mlp_w2  = (const float*)d_in[8];
    const float* mlp_b2  = (const float*)d_in[9];
    const int* ei1       = (const int*)d_in[10];
    const int* batch1    = (const int*)d_in[11];
    const int* ei2       = (const int*)d_in[12];
    const int* batch2    = (const int*)d_in[13];
    float* out = (float*)d_out;

    Ws wc = carve(d_ws, true);
    bool combined = ws_size >= wc.need;
    Ws w = combined ? wc : carve(d_ws, false);

    k_setup<<<226, 256, 0, stream>>>(convW, mlp_w1, mlp_w2, att_src, att_dst,
                                     w.WtC, w.Wt1, w.Wt2, w.Wa, w.p);

    if (combined) {
        pipeline(w, x1, x2, ei1, ei2, batch1, batch2, conv_b,
                 mlp_b1, mlp_b2, w.p, (size_t)GDIM * CDIM, 2, stream);
    } else {
        pipeline(w, x1, x1, ei1, ei1, batch1, batch1, conv_b,
                 mlp_b1, mlp_b2, w.p, 0, 1, stream);
        pipeline(w, x2, x2, ei2, ei2, batch2, batch2, conv_b,
                 mlp_b1, mlp_b2, w.p + GDIM * CDIM, 0, 1, stream);
    }

    k_final<<<CDIM, 64, 0, stream>>>(w.p, out);
}

// Round 8
// 346.954 us; speedup vs baseline: 2.6371x; 1.0806x over previous
//
#include <hip/hip_runtime.h>
#include <cstdint>
#include <cstddef>

#define NNODES 50000
#define NEDGES 500000
#define NTOT (NEDGES + NNODES)
#define HDIM 128
#define CDIM 64
#define GDIM 64
#define NB 250      // buckets
#define NPB 200     // nodes per bucket
#define CHUNK 2048  // edges per partition block
#define NCHB ((NEDGES + CHUNK - 1) / CHUNK)

typedef __bf16 bf16x8 __attribute__((ext_vector_type(8)));
typedef __bf16 bf16x2 __attribute__((ext_vector_type(2)));
typedef float f32x4 __attribute__((ext_vector_type(4)));

// ================= setup: weight casts + Wa vectors + zero p =================

__global__ __launch_bounds__(256) void k_setup(const float* __restrict__ convW,
                                               const float* __restrict__ w1,
                                               const float* __restrict__ w2,
                                               const float* __restrict__ a_s,
                                               const float* __restrict__ a_d,
                                               __bf16* __restrict__ WtC,
                                               __bf16* __restrict__ Wt1,
                                               __bf16* __restrict__ Wt2,
                                               float* __restrict__ Wa,
                                               float* __restrict__ p) {
    int b = blockIdx.x, tid = threadIdx.x;
    if (b < 128) {
        int i = b * 256 + tid;
        int mat = i >> 14, rem = i & 16383;
        int k = rem >> 7, n = rem & 127;
        WtC[mat * 16384 + n * 128 + k] = (__bf16)convW[i];
    } else if (b < 192) {
        int i = (b - 128) * 256 + tid;
        int k = i >> 7, n = i & 127;
        Wt1[n * 128 + k] = (__bf16)w1[i];
    } else if (b < 224) {
        int i = (b - 192) * 256 + tid;
        int k = i >> 6, n = i & 63;
        Wt2[n * 128 + k] = (__bf16)w2[i];
    } else if (b == 224) {
        for (int o = tid; o < 512; o += 256) {
            int l = o >> 8, r = o & 255;
            int type = r >> 7, k = r & 127;
            const float* a = (type ? a_d : a_s) + l * 128;
            const float* Wrow = convW + l * 16384 + k * 128;
            float s = 0.f;
            for (int j = 0; j < 128; j++) s += Wrow[j] * a[j];
            Wa[o] = s;
        }
    } else {
        for (int i = tid; i < 2 * GDIM * CDIM; i += 256) p[i] = 0.f;
    }
}

// ================= CSR build via 2-level bucket sort (y = branch) =================

__global__ __launch_bounds__(256) void k_bhist(const int* __restrict__ ei0,
                                               const int* __restrict__ ei1,
                                               int* __restrict__ bcntB, int e) {
    __shared__ int h[NB];
    const int* dst = (blockIdx.y ? ei1 : ei0) + NEDGES;
    int* bcnt = bcntB + blockIdx.y * NB;
    for (int t = threadIdx.x; t < NB; t += 256) h[t] = 0;
    __syncthreads();
    int base = blockIdx.x * CHUNK;
    int lim = min(base + CHUNK, e);
    for (int i = base + threadIdx.x; i < lim; i += 256) atomicAdd(&h[dst[i] / NPB], 1);
    __syncthreads();
    for (int t = threadIdx.x; t < NB; t += 256)
        if (h[t]) atomicAdd(&bcnt[t], h[t]);
}

__global__ __launch_bounds__(256) void k_bscan(const int* __restrict__ bcntB,
                                               int* __restrict__ boffB,
                                               int* __restrict__ bcurB) {
    __shared__ int s[256];
    int t = threadIdx.x;
    const int* bcnt = bcntB + blockIdx.y * NB;
    int* boff = boffB + blockIdx.y * (NB + 1);
    int* bcur = bcurB + blockIdx.y * NB;
    int v = (t < NB) ? bcnt[t] : 0;
    s[t] = v;
    __syncthreads();
    for (int off = 1; off < 256; off <<= 1) {
        int x = (t >= off) ? s[t - off] : 0;
        __syncthreads();
        s[t] += x;
        __syncthreads();
    }
    if (t < NB) {
        boff[t + 1] = s[t];
        bcur[t] = s[t] - v;  // exclusive
        if (t == 0) boff[0] = 0;
    }
}

__global__ __launch_bounds__(256) void k_part(const int* __restrict__ ei0,
                                              const int* __restrict__ ei1,
                                              int* __restrict__ bcurB,
                                              int2* __restrict__ partB, int e) {
    __shared__ int cnt[NB], boffL[NB], gbase[NB], cur2[NB];
    __shared__ int tmp[256];
    __shared__ int2 staged[CHUNK];
    const int* eis = blockIdx.y ? ei1 : ei0;
    int* bcur = bcurB + blockIdx.y * NB;
    int2* part = partB + blockIdx.y * (size_t)NEDGES;
    int t = threadIdx.x;
    for (int i = t; i < NB; i += 256) { cnt[i] = 0; cur2[i] = 0; }
    __syncthreads();
    int base = blockIdx.x * CHUNK;
    int lim = min(base + CHUNK, e);
    int nloc = lim - base;

    int s_[8], d_[8], b_[8];
    bool v_[8];
#pragma unroll
    for (int k = 0; k < 8; k++) {
        int i = base + k * 256 + t;
        v_[k] = i < lim;
        s_[k] = 0; d_[k] = 0; b_[k] = 0;
        if (v_[k]) {
            s_[k] = eis[i];
            d_[k] = eis[NEDGES + i];
            b_[k] = d_[k] / NPB;
            atomicAdd(&cnt[b_[k]], 1);
        }
    }
    __syncthreads();
    tmp[t] = (t < NB) ? cnt[t] : 0;
    __syncthreads();
    for (int off = 1; off < 256; off <<= 1) {
        int x = (t >= off) ? tmp[t - off] : 0;
        __syncthreads();
        tmp[t] += x;
        __syncthreads();
    }
    if (t < NB) boffL[t] = tmp[t] - cnt[t];
    __syncthreads();
    if (t < NB) {
        int c = cnt[t];
        gbase[t] = c ? atomicAdd(&bcur[t], c) : 0;
    }
    __syncthreads();
#pragma unroll
    for (int k = 0; k < 8; k++) {
        if (v_[k]) {
            int pos = atomicAdd(&cur2[b_[k]], 1);
            staged[boffL[b_[k]] + pos] = make_int2(s_[k], d_[k]);
        }
    }
    __syncthreads();
    for (int i = t; i < nloc; i += 256) {
        int2 r = staged[i];
        int b = r.y / NPB;
        part[gbase[b] + (i - boffL[b])] = r;
    }
}

__global__ __launch_bounds__(256) void k_bdeg(const int2* __restrict__ partB,
                                              const int* __restrict__ boffB,
                                              int* __restrict__ degB, size_t sN) {
    __shared__ int h[NPB];
    int b = blockIdx.x;
    const int* boff = boffB + blockIdx.y * (NB + 1);
    const int2* part = partB + blockIdx.y * (size_t)NEDGES;
    int* deg = degB + blockIdx.y * sN;
    int t = threadIdx.x;
    if (t < NPB) h[t] = 0;
    __syncthreads();
    int beg = boff[b], end = boff[b + 1];
    int n0 = b * NPB;
    for (int i = beg + t; i < end; i += 256) atomicAdd(&h[part[i].y - n0], 1);
    __syncthreads();
    if (t < NPB) deg[n0 + t] = h[t];
}

__device__ inline int block_scan_incl(int v, int* lds) {
    int lane = threadIdx.x & 63, wid = threadIdx.x >> 6;
#pragma unroll
    for (int off = 1; off < 64; off <<= 1) {
        int nv = __shfl_up(v, off);
        if (lane >= off) v += nv;
    }
    if (lane == 63) lds[wid] = v;
    __syncthreads();
    if (wid == 0) {
        int s = (lane < 16) ? lds[lane] : 0;
#pragma unroll
        for (int off = 1; off < 16; off <<= 1) {
            int nv = __shfl_up(s, off);
            if (lane >= off) s += nv;
        }
        if (lane < 16) lds[lane] = s;
    }
    __syncthreads();
    return (wid > 0) ? v + lds[wid - 1] : v;
}

__global__ __launch_bounds__(1024) void k_scan1(const int* __restrict__ degB, int* __restrict__ inclB,
                                                int* __restrict__ bsumsB, size_t sN, int n) {
    __shared__ int lds[16];
    const int* deg = degB + blockIdx.y * sN;
    int* incl = inclB + blockIdx.y * sN;
    int* bsums = bsumsB + blockIdx.y * 64;
    int i = blockIdx.x * 1024 + threadIdx.x;
    int v = (i < n) ? deg[i] : 0;
    int s = block_scan_incl(v, lds);
    if (i < n) incl[i] = s;
    if (threadIdx.x == 1023) bsums[blockIdx.x] = s;
}

__global__ void k_scan2(int* __restrict__ bsumsB, int nb) {
    int* bsums = bsumsB + blockIdx.y * 64;
    int lane = threadIdx.x;
    int v = (lane < nb) ? bsums[lane] : 0;
#pragma unroll
    for (int off = 1; off < 64; off <<= 1) {
        int nv = __shfl_up(v, off);
        if (lane >= off) v += nv;
    }
    if (lane < nb) bsums[lane] = v;
}

// deg counts REAL edges; self loop accounted via +i.
__global__ __launch_bounds__(1024) void k_scan3(const int* __restrict__ inclB,
                                                const int* __restrict__ bsumsB, int* __restrict__ rpB,
                                                size_t sN, size_t sNp1, int n) {
    int i = blockIdx.x * 1024 + threadIdx.x;
    if (i >= n) return;
    const int* incl = inclB + blockIdx.y * sN;
    const int* bsums = bsumsB + blockIdx.y * 64;
    int* row_ptr = rpB + blockIdx.y * sNp1;
    int off = (blockIdx.x > 0) ? bsums[blockIdx.x - 1] : 0;
    row_ptr[i + 1] = incl[i] + off + i + 1;
    if (i == 0) row_ptr[0] = 0;
}

__global__ __launch_bounds__(256) void k_place(const int2* __restrict__ partB,
                                               const int* __restrict__ boffB,
                                               const int* __restrict__ rpB, size_t sNp1,
                                               int* __restrict__ colB, size_t sE) {
    __shared__ int cur[NPB];
    int b = blockIdx.x;
    const int* boff = boffB + blockIdx.y * (NB + 1);
    const int2* part = partB + blockIdx.y * (size_t)NEDGES;
    const int* row_ptr = rpB + blockIdx.y * sNp1;
    int* col = colB + blockIdx.y * sE;
    int t = threadIdx.x;
    int n0 = b * NPB;
    if (t < NPB) {
        int rp = row_ptr[n0 + t];
        cur[t] = rp + 1;
        col[rp] = n0 + t;  // self loop at segment head
    }
    __syncthreads();
    int beg = boff[b], end = boff[b + 1];
    for (int i = beg + t; i < end; i += 256) {
        int2 r = part[i];
        int p = atomicAdd(&cur[r.y - n0], 1);
        col[p] = r.x;
    }
}

// ================= MFMA GEMM (conv layers): [M,128] @ Wt[128][128] -> [M,128] bf16 =================
// AF32: A is f32. Emits alpha_s/alpha_d = A_row . Wa{s,d}

template <bool AF32>
__global__ __launch_bounds__(256) void k_gemm_conv(const float* __restrict__ x0,
                                                   const float* __restrict__ x1,
                                                   const __bf16* __restrict__ Ab, size_t As_,
                                                   const __bf16* __restrict__ Wt,
                                                   const float* __restrict__ Was,
                                                   const float* __restrict__ Wad,
                                                   float* __restrict__ asB, float* __restrict__ adB,
                                                   size_t aS,
                                                   __bf16* __restrict__ OutB, size_t Os_, int M) {
    constexpr int BN = 128;
    __shared__ __align__(16) unsigned short As[64][136];
    __shared__ __align__(16) unsigned short Bs[BN][136];
    const int tid = threadIdx.x;
    const int lane = tid & 63, w = tid >> 6;
    const int row0 = blockIdx.x * 64;
    __bf16* Out = OutB + blockIdx.y * Os_;

#pragma unroll
    for (int t = 0; t < 4; t++) {
        int ch = t * 256 + tid;
        int r = ch >> 4, cx = ch & 15;
        int grow = row0 + r;
        bf16x8 v = {};
        if (grow < M) {
            if (AF32) {
                const float* Ap = (blockIdx.y ? x1 : x0) + (size_t)grow * 128 + cx * 8;
                float4 f0 = *reinterpret_cast<const float4*>(Ap);
                float4 f1 = *reinterpret_cast<const float4*>(Ap + 4);
                v[0] = (__bf16)f0.x; v[1] = (__bf16)f0.y; v[2] = (__bf16)f0.z; v[3] = (__bf16)f0.w;
                v[4] = (__bf16)f1.x; v[5] = (__bf16)f1.y; v[6] = (__bf16)f1.z; v[7] = (__bf16)f1.w;
            } else {
                v = *reinterpret_cast<const bf16x8*>(Ab + blockIdx.y * As_ + (size_t)grow * 128 + cx * 8);
            }
        }
        *reinterpret_cast<bf16x8*>(&As[r][cx * 8]) = v;
    }
#pragma unroll
    for (int t = 0; t < 8; t++) {
        int ch = t * 256 + tid;
        int r = ch >> 4, cx = ch & 15;
        bf16x8 v = *reinterpret_cast<const bf16x8*>(Wt + (size_t)r * 128 + cx * 8);
        *reinterpret_cast<bf16x8*>(&Bs[r][cx * 8]) = v;
    }
    __syncthreads();

    {   // fused alpha: per row dot with Wa vectors
        int row = tid >> 2, seg = tid & 3;
        float ss = 0.f, sd = 0.f;
#pragma unroll
        for (int k = 0; k < 32; k++) {
            int kk = seg * 32 + k;
            float a = __int_as_float(((unsigned)As[row][kk]) << 16);
            ss += a * Was[kk];
            sd += a * Wad[kk];
        }
        ss += __shfl_xor(ss, 1); ss += __shfl_xor(ss, 2);
        sd += __shfl_xor(sd, 1); sd += __shfl_xor(sd, 2);
        if (seg == 0) {
            int grow = row0 + row;
            if (grow < M) {
                (asB + blockIdx.y * aS)[grow] = ss;
                (adB + blockIdx.y * aS)[grow] = sd;
            }
        }
    }

    const int wr0 = (w >> 1) * 32;
    const int wc0 = (w & 1) * 64;
    f32x4 acc[2][4] = {};

#pragma unroll
    for (int ks = 0; ks < 4; ks++) {
        const int koff = ks * 32 + (lane >> 4) * 8;
        bf16x8 af[2], bfr[4];
#pragma unroll
        for (int mf = 0; mf < 2; mf++)
            af[mf] = *reinterpret_cast<const bf16x8*>(&As[wr0 + mf * 16 + (lane & 15)][koff]);
#pragma unroll
        for (int nf = 0; nf < 4; nf++)
            bfr[nf] = *reinterpret_cast<const bf16x8*>(&Bs[wc0 + nf * 16 + (lane & 15)][koff]);
#pragma unroll
        for (int mf = 0; mf < 2; mf++)
#pragma unroll
            for (int nf = 0; nf < 4; nf++)
                acc[mf][nf] = __builtin_amdgcn_mfma_f32_16x16x32_bf16(af[mf], bfr[nf], acc[mf][nf], 0, 0, 0);
    }

#pragma unroll
    for (int mf = 0; mf < 2; mf++) {
#pragma unroll
        for (int r = 0; r < 4; r++) {
            int row = row0 + wr0 + mf * 16 + (lane >> 4) * 4 + r;
            if (row >= M) continue;
#pragma unroll
            for (int nf = 0; nf < 4; nf++) {
                int colc = wc0 + nf * 16 + (lane & 15);
                Out[(size_t)row * BN + colc] = (__bf16)acc[mf][nf][r];
            }
        }
    }
}

// ================= fused segment-softmax + aggregate + bias + ELU =================
// one wave per dst node; 16 lanes x 16B cover one 256B h row; all-lane epilogue.

__global__ __launch_bounds__(256) void k_gat_agg(const __bf16* __restrict__ hB, size_t hS,
                                                 const float* __restrict__ asB,
                                                 const float* __restrict__ adB, size_t aS,
                                                 const int* __restrict__ rpB, size_t sNp1,
                                                 const int* __restrict__ colB, size_t sE,
                                                 const float* __restrict__ bias,
                                                 __bf16* __restrict__ outB, size_t oS, int n) {
    int node = blockIdx.x * 4 + (threadIdx.x >> 6);
    int lane = threadIdx.x & 63;
    if (node >= n) return;
    const float* alpha_s = asB + blockIdx.y * aS;
    const int* row_ptr = rpB + blockIdx.y * sNp1;
    const int* col = colB + blockIdx.y * sE;
    const char* hbase = (const char*)(hB + blockIdx.y * hS);
    float ad = (adB + blockIdx.y * aS)[node];
    int beg = row_ptr[node], end = row_ptr[node + 1];
    int deg = end - beg;
    int sub = lane >> 4, fo = lane & 15;
    int foff = fo * 16;

    float acc[8] = {0.f, 0.f, 0.f, 0.f, 0.f, 0.f, 0.f, 0.f};

    if (deg <= 64) {
        bool v = lane < deg;
        int c = 0;
        float e = -1e30f;
        if (v) {
            c = col[beg + lane];
            e = alpha_s[c] + ad;
            e = (e > 0.f) ? e : 0.2f * e;
        }
        float m = e;
#pragma unroll
        for (int off = 32; off; off >>= 1) m = fmaxf(m, __shfl_xor(m, off));
        float ex = v ? __expf(e - m) : 0.f;
        float den = ex;
#pragma unroll
        for (int off = 32; off; off >>= 1) den += __shfl_xor(den, off);
        float wn = ex / den;

        int nIter = (deg + 3) >> 2;
        int k = sub;
        for (int t = 0; t < nIter; t += 2) {
            int k1 = k & 63, k2 = (k + 4) & 63;
            int c1 = __shfl(c, k1); float w1 = __shfl(wn, k1);
            int c2 = __shfl(c, k2); float w2 = __shfl(wn, k2);
            bool v1 = k < deg, v2 = (k + 4) < deg;
            w1 = v1 ? w1 : 0.f; c1 = v1 ? c1 : 0;
            w2 = v2 ? w2 : 0.f; c2 = v2 ? c2 : 0;
            bf16x8 h1 = *reinterpret_cast<const bf16x8*>(hbase + (c1 << 8) + foff);
            bf16x8 h2 = *reinterpret_cast<const bf16x8*>(hbase + (c2 << 8) + foff);
#pragma unroll
            for (int q = 0; q < 8; q++) acc[q] += w1 * (float)h1[q] + w2 * (float)h2[q];
            k += 8;
        }
    } else {
        float m = -1e30f;
        for (int i = beg + lane; i < end; i += 64) {
            float e = alpha_s[col[i]] + ad;
            e = (e > 0.f) ? e : 0.2f * e;
            m = fmaxf(m, e);
        }
#pragma unroll
        for (int off = 32; off; off >>= 1) m = fmaxf(m, __shfl_xor(m, off));
        float den = 0.f;
        for (int i = beg + lane; i < end; i += 64) {
            float e = alpha_s[col[i]] + ad;
            e = (e > 0.f) ? e : 0.2f * e;
            den += __expf(e - m);
        }
#pragma unroll
        for (int off = 32; off; off >>= 1) den += __shfl_xor(den, off);
        float rinv = 1.f / den;
        for (int i = beg + sub; i < end; i += 4) {
            int cc = col[i];
            float e = alpha_s[cc] + ad;
            e = (e > 0.f) ? e : 0.2f * e;
            float wv = __expf(e - m) * rinv;
            bf16x8 hv = *reinterpret_cast<const bf16x8*>(hbase + (cc << 8) + foff);
#pragma unroll
            for (int q = 0; q < 8; q++) acc[q] += wv * (float)hv[q];
        }
    }

#pragma unroll
    for (int q = 0; q < 8; q++) {
        acc[q] += __shfl_xor(acc[q], 16);
        acc[q] += __shfl_xor(acc[q], 32);
    }
    // all-lane epilogue: lane group `sub` handles features fo*8 + {2sub, 2sub+1}
    float2 bv = *reinterpret_cast<const float2*>(bias + fo * 8 + 2 * sub);
    float x0 = (sub & 2) ? ((sub & 1) ? acc[6] : acc[4]) : ((sub & 1) ? acc[2] : acc[0]);
    float x1 = (sub & 2) ? ((sub & 1) ? acc[7] : acc[5]) : ((sub & 1) ? acc[3] : acc[1]);
    x0 += bv.x; x1 += bv.y;
    x0 = (x0 > 0.f) ? x0 : __expf(x0) - 1.f;
    x1 = (x1 > 0.f) ? x1 : __expf(x1) - 1.f;
    bf16x2 ov;
    ov.x = (__bf16)x0; ov.y = (__bf16)x1;
    char* ob = (char*)(outB + blockIdx.y * oS) + ((unsigned)node << 8) + foff + sub * 4;
    *reinterpret_cast<unsigned int*>(ob) = __builtin_bit_cast(unsigned int, ov);
}

// ================= fused MLP (relu GEMM -> GEMM) + segment pool =================
// block = 64 rows; t kept in LDS; pool via per-wave reduced atomics.

__global__ __launch_bounds__(256) void k_mlp_pool(const __bf16* __restrict__ AbB, size_t As_,
                                                  const __bf16* __restrict__ Wt1,
                                                  const __bf16* __restrict__ Wt2,
                                                  const float* __restrict__ b1,
                                                  const float* __restrict__ b2,
                                                  const int* __restrict__ bat0,
                                                  const int* __restrict__ bat1,
                                                  float* __restrict__ pB, size_t pS, int M) {
    __shared__ __align__(16) unsigned short As[64][136];
    __shared__ __align__(16) unsigned short Bs[128][136];
    const int tid = threadIdx.x;
    const int lane = tid & 63, w = tid >> 6;
    const int row0 = blockIdx.x * 64;
    const __bf16* Ab = AbB + blockIdx.y * As_;
    const int* batch = blockIdx.y ? bat1 : bat0;
    float* p = pB + blockIdx.y * pS;

    // stage z tile + Wt1
#pragma unroll
    for (int t = 0; t < 4; t++) {
        int ch = t * 256 + tid;
        int r = ch >> 4, cx = ch & 15;
        int grow = row0 + r;
        bf16x8 v = {};
        if (grow < M) v = *reinterpret_cast<const bf16x8*>(Ab + (size_t)grow * 128 + cx * 8);
        *reinterpret_cast<bf16x8*>(&As[r][cx * 8]) = v;
    }
#pragma unroll
    for (int t = 0; t < 8; t++) {
        int ch = t * 256 + tid;
        int r = ch >> 4, cx = ch & 15;
        bf16x8 v = *reinterpret_cast<const bf16x8*>(Wt1 + (size_t)r * 128 + cx * 8);
        *reinterpret_cast<bf16x8*>(&Bs[r][cx * 8]) = v;
    }
    __syncthreads();

    // stage 1: t = relu(z @ W1 + b1), 2x2 wave grid
    {
        const int wr0 = (w >> 1) * 32;
        const int wc0 = (w & 1) * 64;
        f32x4 acc[2][4] = {};
#pragma unroll
        for (int ks = 0; ks < 4; ks++) {
            const int koff = ks * 32 + (lane >> 4) * 8;
            bf16x8 af[2], bfr[4];
#pragma unroll
            for (int mf = 0; mf < 2; mf++)
                af[mf] = *reinterpret_cast<const bf16x8*>(&As[wr0 + mf * 16 + (lane & 15)][koff]);
#pragma unroll
            for (int nf = 0; nf < 4; nf++)
                bfr[nf] = *reinterpret_cast<const bf16x8*>(&Bs[wc0 + nf * 16 + (lane & 15)][koff]);
#pragma unroll
            for (int mf = 0; mf < 2; mf++)
#pragma unroll
                for (int nf = 0; nf < 4; nf++)
                    acc[mf][nf] = __builtin_amdgcn_mfma_f32_16x16x32_bf16(af[mf], bfr[nf], acc[mf][nf], 0, 0, 0);
        }
        __syncthreads();  // all As/Bs reads done
        // write t into As; stage Wt2 into Bs[0..64]
#pragma unroll
        for (int mf = 0; mf < 2; mf++)
#pragma unroll
            for (int r = 0; r < 4; r++) {
                int row = wr0 + mf * 16 + (lane >> 4) * 4 + r;
#pragma unroll
                for (int nf = 0; nf < 4; nf++) {
                    int colc = wc0 + nf * 16 + (lane & 15);
                    float v = fmaxf(acc[mf][nf][r] + b1[colc], 0.f);
                    As[row][colc] = __builtin_bit_cast(unsigned short, (__bf16)v);
                }
            }
#pragma unroll
        for (int t = 0; t < 4; t++) {
            int ch = t * 256 + tid;
            int r = ch >> 4, cx = ch & 15;
            bf16x8 v = *reinterpret_cast<const bf16x8*>(Wt2 + (size_t)r * 128 + cx * 8);
            *reinterpret_cast<bf16x8*>(&Bs[r][cx * 8]) = v;
        }
        __syncthreads();
    }

    // stage 2: u = t @ W2 + b2; pool into p
    const int wr2 = w * 16;
    f32x4 acc2[4] = {};
#pragma unroll
    for (int ks = 0; ks < 4; ks++) {
        const int koff = ks * 32 + (lane >> 4) * 8;
        bf16x8 a2 = *reinterpret_cast<const bf16x8*>(&As[wr2 + (lane & 15)][koff]);
#pragma unroll
        for (int nf = 0; nf < 4; nf++) {
            bf16x8 bf2 = *reinterpret_cast<const bf16x8*>(&Bs[nf * 16 + (lane & 15)][koff]);
            acc2[nf] = __builtin_amdgcn_mfma_f32_16x16x32_bf16(a2, bf2, acc2[nf], 0, 0, 0);
        }
    }

    int q = lane >> 4, c = lane & 15;
    bool full = (row0 + 63) < M;
    int g0 = batch[min(row0, M - 1)];
    int g1 = batch[min(row0 + 63, M - 1)];
    if (full && g0 == g1) {
        float s0 = acc2[0][0] + acc2[0][1] + acc2[0][2] + acc2[0][3];
        float s1 = acc2[1][0] + acc2[1][1] + acc2[1][2] + acc2[1][3];
        float s2 = acc2[2][0] + acc2[2][1] + acc2[2][2] + acc2[2][3];
        float s3 = acc2[3][0] + acc2[3][1] + acc2[3][2] + acc2[3][3];
        s0 += __shfl_xor(s0, 16); s0 += __shfl_xor(s0, 32);
        s1 += __shfl_xor(s1, 16); s1 += __shfl_xor(s1, 32);
        s2 += __shfl_xor(s2, 16); s2 += __shfl_xor(s2, 32);
        s3 += __shfl_xor(s3, 16); s3 += __shfl_xor(s3, 32);
        float v = (q & 2) ? ((q & 1) ? s3 : s2) : ((q & 1) ? s1 : s0);
        v += 16.f * b2[q * 16 + c];
        atomicAdd(&p[g0 * CDIM + q * 16 + c], v);
    } else {
        float b2v[4];
#pragma unroll
        for (int nf = 0; nf < 4; nf++) b2v[nf] = b2[nf * 16 + c];
#pragma unroll
        for (int r = 0; r < 4; r++) {
            int row = row0 + wr2 + q * 4 + r;
            if (row >= M) continue;
            int g = batch[row];
#pragma unroll
            for (int nf = 0; nf < 4; nf++)
                atomicAdd(&p[g * CDIM + nf * 16 + c], acc2[nf][r] + b2v[nf]);
        }
    }
}

// ================= final p1^T @ p2 =================

__global__ __launch_bounds__(64) void k_final(const float* __restrict__ p, float* __restrict__ out) {
    int i = blockIdx.x;
    int j = threadIdx.x;
    const float* p1 = p;
    const float* p2 = p + GDIM * CDIM;
    float s = 0.f;
    for (int g = 0; g < GDIM; ++g) s += p1[g * CDIM + i] * p2[g * CDIM + j];
    out[i * CDIM + j] = s;
}

// ================= host side =================

static inline size_t align_up(size_t x, size_t a) { return (x + a - 1) & ~(a - 1); }

struct Ws {
    __bf16 *Hb, *Yb;
    __bf16 *WtC, *Wt1, *Wt2;
    float *alpha_s, *alpha_d, *Wa, *p;
    int *deg, *incl, *row_ptr, *bsums, *col;
    int *bcnt, *boff, *bcur;
    int2* part;
    size_t sNH, sN, sNp1, sE;
    size_t need;
};

static Ws carve(void* ws, bool combined) {
    char* p = (char*)ws;
    size_t off = 0;
    Ws w;
    int nb = combined ? 2 : 1;
    auto take = [&](size_t bytes) {
        char* r = p + off;
        off = align_up(off + bytes, 256);
        return r;
    };
    w.Hb = (__bf16*)take((size_t)nb * NNODES * HDIM * 2);
    w.Yb = (__bf16*)take((size_t)nb * NNODES * HDIM * 2);
    w.alpha_s = (float*)take((size_t)nb * NNODES * 4);
    w.alpha_d = (float*)take((size_t)nb * NNODES * 4);
    w.col = (int*)take((size_t)nb * NTOT * 4);
    w.part = (int2*)take((size_t)nb * NEDGES * 8);
    w.deg = (int*)take((size_t)nb * NNODES * 4);
    w.incl = (int*)take((size_t)nb * NNODES * 4);
    w.row_ptr = (int*)take((size_t)nb * (NNODES + 1) * 4);
    w.bsums = (int*)take((size_t)2 * 64 * 4);
    w.bcnt = (int*)take((size_t)2 * NB * 4);
    w.boff = (int*)take((size_t)2 * (NB + 1) * 4);
    w.bcur = (int*)take((size_t)2 * NB * 4);
    w.WtC = (__bf16*)take((size_t)2 * HDIM * HDIM * 2);
    w.Wt1 = (__bf16*)take((size_t)HDIM * HDIM * 2);
    w.Wt2 = (__bf16*)take((size_t)HDIM * CDIM * 2);
    w.Wa = (float*)take((size_t)512 * 4);
    w.p = (float*)take((size_t)2 * GDIM * CDIM * 4);
    w.need = off;
    size_t s = combined ? 1 : 0;
    w.sNH = s * (size_t)NNODES * HDIM;
    w.sN = s * (size_t)NNODES;
    w.sNp1 = s * (size_t)(NNODES + 1);
    w.sE = s * (size_t)NTOT;
    return w;
}

static void pipeline(const Ws& w, const float* xA, const float* xB,
                     const int* eiA, const int* eiB,
                     const int* batA, const int* batB,
                     const float* conv_b, const float* b1, const float* b2,
                     float* pbase, size_t pstride, int yc, hipStream_t stream) {
    const int N = NNODES, E = NEDGES;
    int nb = (N + 1023) / 1024;
    dim3 gC(NCHB, yc), gB(NB, yc), g1(1, yc), gS(nb, yc);
    dim3 gW((N + 3) / 4, yc);
    dim3 gG((N + 63) / 64, yc);

    // ---- CSR build (bucketed, write-local) ----
    hipMemsetAsync(w.bcnt, 0, (size_t)yc * NB * 4, stream);
    k_bhist<<<gC, 256, 0, stream>>>(eiA, eiB, w.bcnt, E);
    k_bscan<<<g1, 256, 0, stream>>>(w.bcnt, w.boff, w.bcur);
    k_part<<<gC, 256, 0, stream>>>(eiA, eiB, w.bcur, w.part, E);
    k_bdeg<<<gB, 256, 0, stream>>>(w.part, w.boff, w.deg, w.sN);
    k_scan1<<<gS, 1024, 0, stream>>>(w.deg, w.incl, w.bsums, w.sN, N);
    k_scan2<<<g1, 64, 0, stream>>>(w.bsums, nb);
    k_scan3<<<gS, 1024, 0, stream>>>(w.incl, w.bsums, w.row_ptr, w.sN, w.sNp1, N);
    k_place<<<gB, 256, 0, stream>>>(w.part, w.boff, w.row_ptr, w.sNp1, w.col, w.sE);

    // ---- conv layer 0 ----
    k_gemm_conv<true><<<gG, 256, 0, stream>>>(
        xA, xB, nullptr, 0, w.WtC, w.Wa, w.Wa + 128,
        w.alpha_s, w.alpha_d, w.sN, w.Hb, w.sNH, N);
    k_gat_agg<<<gW, 256, 0, stream>>>(w.Hb, w.sNH, w.alpha_s, w.alpha_d, w.sN,
                                      w.row_ptr, w.sNp1, w.col, w.sE, conv_b, w.Yb, w.sNH, N);
    // ---- conv layer 1 ----
    k_gemm_conv<false><<<gG, 256, 0, stream>>>(
        nullptr, nullptr, w.Yb, w.sNH, w.WtC + HDIM * HDIM, w.Wa + 256, w.Wa + 384,
        w.alpha_s, w.alpha_d, w.sN, w.Hb, w.sNH, N);
    k_gat_agg<<<gW, 256, 0, stream>>>(w.Hb, w.sNH, w.alpha_s, w.alpha_d, w.sN,
                                      w.row_ptr, w.sNp1, w.col, w.sE, conv_b + HDIM, w.Yb, w.sNH, N);
    // ---- fused MLP + pool ----
    k_mlp_pool<<<gG, 256, 0, stream>>>(w.Yb, w.sNH, w.Wt1, w.Wt2, b1, b2,
                                       batA, batB, pbase, pstride, N);
}

extern "C" void kernel_launch(void* const* d_in, const int* in_sizes, int n_in, void* d_out,
                              int out_size, void* d_ws, size_t ws_size, hipStream_t stream) {
    const float* x1      = (const float*)d_in[0];
    const float* x2      = (const float*)d_in[1];
    const float* convW   = (const float*)d_in[2];
    const float* att_src = (const float*)d_in[3];
    const float* att_dst = (const float*)d_in[4];
    const float* conv_b  = (const float*)d_in[5];
    const float* mlp_w1  = (const float*)d_in[6];
    const float* mlp_b1  = (const float*)d_in[7];
    const float* mlp_w2  = (const float*)d_in[8];
    const float* mlp_b2  = (const float*)d_in[9];
    const int* ei1       = (const int*)d_in[10];
    const int* batch1    = (const int*)d_in[11];
    const int* ei2       = (const int*)d_in[12];
    const int* batch2    = (const int*)d_in[13];
    float* out = (float*)d_out;

    Ws wc = carve(d_ws, true);
    bool combined = ws_size >= wc.need;
    Ws w = combined ? wc : carve(d_ws, false);

    k_setup<<<226, 256, 0, stream>>>(convW, mlp_w1, mlp_w2, att_src, att_dst,
                                     w.WtC, w.Wt1, w.Wt2, w.Wa, w.p);

    if (combined) {
        pipeline(w, x1, x2, ei1, ei2, batch1, batch2, conv_b,
                 mlp_b1, mlp_b2, w.p, (size_t)GDIM * CDIM, 2, stream);
    } else {
        pipeline(w, x1, x1, ei1, ei1, batch1, batch1, conv_b,
                 mlp_b1, mlp_b2, w.p, 0, 1, stream);
        pipeline(w, x2, x2, ei2, ei2, batch2, batch2, conv_b,
                 mlp_b1, mlp_b2, w.p + GDIM * CDIM, 0, 1, stream);
    }

    k_final<<<CDIM, 64, 0, stream>>>(w.p, out);
}

// Round 9
// 346.919 us; speedup vs baseline: 2.6374x; 1.0001x over previous
//
#include <hip/hip_runtime.h>
#include <cstdint>
#include <cstddef>

#define NNODES 50000
#define NEDGES 500000
#define NTOT (NEDGES + NNODES)
#define HDIM 128
#define CDIM 64
#define GDIM 64
#define NB 250      // buckets
#define NPB 200     // nodes per bucket
#define CHUNK 2048  // edges per partition block
#define NCHB ((NEDGES + CHUNK - 1) / CHUNK)

typedef __bf16 bf16x8 __attribute__((ext_vector_type(8)));
typedef __bf16 bf16x2 __attribute__((ext_vector_type(2)));
typedef float f32x4 __attribute__((ext_vector_type(4)));

// ================= setup: weight casts + Wa vectors + zero p =================

__global__ __launch_bounds__(256) void k_setup(const float* __restrict__ convW,
                                               const float* __restrict__ w1,
                                               const float* __restrict__ w2,
                                               const float* __restrict__ a_s,
                                               const float* __restrict__ a_d,
                                               __bf16* __restrict__ WtC,
                                               __bf16* __restrict__ Wt1,
                                               __bf16* __restrict__ Wt2,
                                               float* __restrict__ Wa,
                                               float* __restrict__ p) {
    int b = blockIdx.x, tid = threadIdx.x;
    if (b < 128) {
        int i = b * 256 + tid;
        int mat = i >> 14, rem = i & 16383;
        int k = rem >> 7, n = rem & 127;
        WtC[mat * 16384 + n * 128 + k] = (__bf16)convW[i];
    } else if (b < 192) {
        int i = (b - 128) * 256 + tid;
        int k = i >> 7, n = i & 127;
        Wt1[n * 128 + k] = (__bf16)w1[i];
    } else if (b < 224) {
        int i = (b - 192) * 256 + tid;
        int k = i >> 6, n = i & 63;
        Wt2[n * 128 + k] = (__bf16)w2[i];
    } else if (b == 224) {
        for (int o = tid; o < 512; o += 256) {
            int l = o >> 8, r = o & 255;
            int type = r >> 7, k = r & 127;
            const float* a = (type ? a_d : a_s) + l * 128;
            const float* Wrow = convW + l * 16384 + k * 128;
            float s = 0.f;
            for (int j = 0; j < 128; j++) s += Wrow[j] * a[j];
            Wa[o] = s;
        }
    } else {
        for (int i = tid; i < 2 * GDIM * CDIM; i += 256) p[i] = 0.f;
    }
}

// ================= CSR build via 2-level bucket sort (y = branch) =================

__global__ __launch_bounds__(256) void k_bhist(const int* __restrict__ ei0,
                                               const int* __restrict__ ei1,
                                               int* __restrict__ bcntB, int e) {
    __shared__ int h[NB];
    const int* dst = (blockIdx.y ? ei1 : ei0) + NEDGES;
    int* bcnt = bcntB + blockIdx.y * NB;
    for (int t = threadIdx.x; t < NB; t += 256) h[t] = 0;
    __syncthreads();
    int base = blockIdx.x * CHUNK;
    int lim = min(base + CHUNK, e);
    for (int i = base + threadIdx.x; i < lim; i += 256) atomicAdd(&h[dst[i] / NPB], 1);
    __syncthreads();
    for (int t = threadIdx.x; t < NB; t += 256)
        if (h[t]) atomicAdd(&bcnt[t], h[t]);
}

__global__ __launch_bounds__(256) void k_bscan(const int* __restrict__ bcntB,
                                               int* __restrict__ boffB,
                                               int* __restrict__ bcurB) {
    __shared__ int s[256];
    int t = threadIdx.x;
    const int* bcnt = bcntB + blockIdx.y * NB;
    int* boff = boffB + blockIdx.y * (NB + 1);
    int* bcur = bcurB + blockIdx.y * NB;
    int v = (t < NB) ? bcnt[t] : 0;
    s[t] = v;
    __syncthreads();
    for (int off = 1; off < 256; off <<= 1) {
        int x = (t >= off) ? s[t - off] : 0;
        __syncthreads();
        s[t] += x;
        __syncthreads();
    }
    if (t < NB) {
        boff[t + 1] = s[t];
        bcur[t] = s[t] - v;  // exclusive
        if (t == 0) boff[0] = 0;
    }
}

__global__ __launch_bounds__(256) void k_part(const int* __restrict__ ei0,
                                              const int* __restrict__ ei1,
                                              int* __restrict__ bcurB,
                                              int2* __restrict__ partB, int e) {
    __shared__ int cnt[NB], boffL[NB], gbase[NB], cur2[NB];
    __shared__ int tmp[256];
    __shared__ int2 staged[CHUNK];
    const int* eis = blockIdx.y ? ei1 : ei0;
    int* bcur = bcurB + blockIdx.y * NB;
    int2* part = partB + blockIdx.y * (size_t)NEDGES;
    int t = threadIdx.x;
    for (int i = t; i < NB; i += 256) { cnt[i] = 0; cur2[i] = 0; }
    __syncthreads();
    int base = blockIdx.x * CHUNK;
    int lim = min(base + CHUNK, e);
    int nloc = lim - base;

    int s_[8], d_[8], b_[8];
    bool v_[8];
#pragma unroll
    for (int k = 0; k < 8; k++) {
        int i = base + k * 256 + t;
        v_[k] = i < lim;
        s_[k] = 0; d_[k] = 0; b_[k] = 0;
        if (v_[k]) {
            s_[k] = eis[i];
            d_[k] = eis[NEDGES + i];
            b_[k] = d_[k] / NPB;
            atomicAdd(&cnt[b_[k]], 1);
        }
    }
    __syncthreads();
    tmp[t] = (t < NB) ? cnt[t] : 0;
    __syncthreads();
    for (int off = 1; off < 256; off <<= 1) {
        int x = (t >= off) ? tmp[t - off] : 0;
        __syncthreads();
        tmp[t] += x;
        __syncthreads();
    }
    if (t < NB) boffL[t] = tmp[t] - cnt[t];
    __syncthreads();
    if (t < NB) {
        int c = cnt[t];
        gbase[t] = c ? atomicAdd(&bcur[t], c) : 0;
    }
    __syncthreads();
#pragma unroll
    for (int k = 0; k < 8; k++) {
        if (v_[k]) {
            int pos = atomicAdd(&cur2[b_[k]], 1);
            staged[boffL[b_[k]] + pos] = make_int2(s_[k], d_[k]);
        }
    }
    __syncthreads();
    for (int i = t; i < nloc; i += 256) {
        int2 r = staged[i];
        int b = r.y / NPB;
        part[gbase[b] + (i - boffL[b])] = r;
    }
}

// per-bucket: histogram -> LDS scan -> row_ptr + self-loop col + place edges
__global__ __launch_bounds__(256) void k_place(const int2* __restrict__ partB,
                                               const int* __restrict__ boffB,
                                               int* __restrict__ rpB, size_t sNp1,
                                               int* __restrict__ colB, size_t sE) {
    __shared__ int h[NPB];
    __shared__ int lds4[4];
    int b = blockIdx.x;
    const int* boff = boffB + blockIdx.y * (NB + 1);
    const int2* part = partB + blockIdx.y * (size_t)NEDGES;
    int* row_ptr = rpB + blockIdx.y * sNp1;
    int* col = colB + blockIdx.y * sE;
    int t = threadIdx.x;
    int n0 = b * NPB;
    if (t < NPB) h[t] = 0;
    __syncthreads();
    int beg = boff[b], end = boff[b + 1];
    for (int i = beg + t; i < end; i += 256) atomicAdd(&h[part[i].y - n0], 1);
    __syncthreads();
    int v = (t < NPB) ? h[t] : 0;
    // 256-thread inclusive scan (4 waves)
    int lane = t & 63, wid = t >> 6;
    int incl = v;
#pragma unroll
    for (int off = 1; off < 64; off <<= 1) {
        int nv = __shfl_up(incl, off);
        if (lane >= off) incl += nv;
    }
    if (lane == 63) lds4[wid] = incl;
    __syncthreads();
    if (t == 0) {
        int s = 0;
#pragma unroll
        for (int j = 0; j < 4; j++) { s += lds4[j]; lds4[j] = s; }
    }
    __syncthreads();
    if (wid > 0) incl += lds4[wid - 1];
    if (t < NPB) {
        int rp_end = beg + n0 + incl + t + 1;   // row_ptr[n0+t+1]
        row_ptr[n0 + t + 1] = rp_end;
        int rp_start = rp_end - v - 1;
        col[rp_start] = n0 + t;                  // self loop at segment head
        h[t] = rp_start + 1;                     // cursor
        if (b == 0 && t == 0) row_ptr[0] = 0;
    }
    __syncthreads();
    for (int i = beg + t; i < end; i += 256) {
        int2 r = part[i];
        int p = atomicAdd(&h[r.y - n0], 1);
        col[p] = r.x;
    }
}

// ================= MFMA GEMM (conv layers): [M,128] @ Wt[128][128] -> [M,128] bf16 =================
// AF32: A is f32. Emits alpha_s/alpha_d = A_row . Wa{s,d}

template <bool AF32>
__global__ __launch_bounds__(256) void k_gemm_conv(const float* __restrict__ x0,
                                                   const float* __restrict__ x1,
                                                   const __bf16* __restrict__ Ab, size_t As_,
                                                   const __bf16* __restrict__ Wt,
                                                   const float* __restrict__ Was,
                                                   const float* __restrict__ Wad,
                                                   float* __restrict__ asB, float* __restrict__ adB,
                                                   size_t aS,
                                                   __bf16* __restrict__ OutB, size_t Os_, int M) {
    constexpr int BN = 128;
    __shared__ __align__(16) unsigned short As[64][136];
    __shared__ __align__(16) unsigned short Bs[BN][136];
    const int tid = threadIdx.x;
    const int lane = tid & 63, w = tid >> 6;
    const int row0 = blockIdx.x * 64;
    __bf16* Out = OutB + blockIdx.y * Os_;

#pragma unroll
    for (int t = 0; t < 4; t++) {
        int ch = t * 256 + tid;
        int r = ch >> 4, cx = ch & 15;
        int grow = row0 + r;
        bf16x8 v = {};
        if (grow < M) {
            if (AF32) {
                const float* Ap = (blockIdx.y ? x1 : x0) + (size_t)grow * 128 + cx * 8;
                float4 f0 = *reinterpret_cast<const float4*>(Ap);
                float4 f1 = *reinterpret_cast<const float4*>(Ap + 4);
                v[0] = (__bf16)f0.x; v[1] = (__bf16)f0.y; v[2] = (__bf16)f0.z; v[3] = (__bf16)f0.w;
                v[4] = (__bf16)f1.x; v[5] = (__bf16)f1.y; v[6] = (__bf16)f1.z; v[7] = (__bf16)f1.w;
            } else {
                v = *reinterpret_cast<const bf16x8*>(Ab + blockIdx.y * As_ + (size_t)grow * 128 + cx * 8);
            }
        }
        *reinterpret_cast<bf16x8*>(&As[r][cx * 8]) = v;
    }
#pragma unroll
    for (int t = 0; t < 8; t++) {
        int ch = t * 256 + tid;
        int r = ch >> 4, cx = ch & 15;
        bf16x8 v = *reinterpret_cast<const bf16x8*>(Wt + (size_t)r * 128 + cx * 8);
        *reinterpret_cast<bf16x8*>(&Bs[r][cx * 8]) = v;
    }
    __syncthreads();

    {   // fused alpha: per row dot with Wa vectors
        int row = tid >> 2, seg = tid & 3;
        float ss = 0.f, sd = 0.f;
#pragma unroll
        for (int k = 0; k < 32; k++) {
            int kk = seg * 32 + k;
            float a = __int_as_float(((unsigned)As[row][kk]) << 16);
            ss += a * Was[kk];
            sd += a * Wad[kk];
        }
        ss += __shfl_xor(ss, 1); ss += __shfl_xor(ss, 2);
        sd += __shfl_xor(sd, 1); sd += __shfl_xor(sd, 2);
        if (seg == 0) {
            int grow = row0 + row;
            if (grow < M) {
                (asB + blockIdx.y * aS)[grow] = ss;
                (adB + blockIdx.y * aS)[grow] = sd;
            }
        }
    }

    const int wr0 = (w >> 1) * 32;
    const int wc0 = (w & 1) * 64;
    f32x4 acc[2][4] = {};

#pragma unroll
    for (int ks = 0; ks < 4; ks++) {
        const int koff = ks * 32 + (lane >> 4) * 8;
        bf16x8 af[2], bfr[4];
#pragma unroll
        for (int mf = 0; mf < 2; mf++)
            af[mf] = *reinterpret_cast<const bf16x8*>(&As[wr0 + mf * 16 + (lane & 15)][koff]);
#pragma unroll
        for (int nf = 0; nf < 4; nf++)
            bfr[nf] = *reinterpret_cast<const bf16x8*>(&Bs[wc0 + nf * 16 + (lane & 15)][koff]);
#pragma unroll
        for (int mf = 0; mf < 2; mf++)
#pragma unroll
            for (int nf = 0; nf < 4; nf++)
                acc[mf][nf] = __builtin_amdgcn_mfma_f32_16x16x32_bf16(af[mf], bfr[nf], acc[mf][nf], 0, 0, 0);
    }

#pragma unroll
    for (int mf = 0; mf < 2; mf++) {
#pragma unroll
        for (int r = 0; r < 4; r++) {
            int row = row0 + wr0 + mf * 16 + (lane >> 4) * 4 + r;
            if (row >= M) continue;
#pragma unroll
            for (int nf = 0; nf < 4; nf++) {
                int colc = wc0 + nf * 16 + (lane & 15);
                Out[(size_t)row * BN + colc] = (__bf16)acc[mf][nf][r];
            }
        }
    }
}

// ================= fused segment-softmax + aggregate + bias + ELU =================
// 16-lane group per node (4 nodes/wave); lane owns a 16B feature slice.

__global__ __launch_bounds__(256) void k_gat_agg(const __bf16* __restrict__ hB, size_t hS,
                                                 const float* __restrict__ asB,
                                                 const float* __restrict__ adB, size_t aS,
                                                 const int* __restrict__ rpB, size_t sNp1,
                                                 const int* __restrict__ colB, size_t sE,
                                                 const float* __restrict__ bias,
                                                 __bf16* __restrict__ outB, size_t oS, int n) {
    int grp = threadIdx.x >> 4;
    int node = blockIdx.x * 16 + grp;
    int l = threadIdx.x & 15;
    if (node >= n) return;
    const float* alpha_s = asB + blockIdx.y * aS;
    const int* row_ptr = rpB + blockIdx.y * sNp1;
    const int* col = colB + blockIdx.y * sE;
    const char* hbase = (const char*)(hB + blockIdx.y * hS);
    float ad = (adB + blockIdx.y * aS)[node];
    int beg = row_ptr[node], end = row_ptr[node + 1];
    int deg = end - beg;
    int foff = l * 16;

    float acc[8] = {0.f, 0.f, 0.f, 0.f, 0.f, 0.f, 0.f, 0.f};

    if (deg <= 16) {
        bool v = l < deg;
        int c = 0;
        float e = -1e30f;
        if (v) {
            c = col[beg + l];
            float t = alpha_s[c] + ad;
            e = (t > 0.f) ? t : 0.2f * t;
        }
        float m = e;
#pragma unroll
        for (int off = 8; off; off >>= 1) m = fmaxf(m, __shfl_xor(m, off));
        float ex = v ? __expf(e - m) : 0.f;
        float den = ex;
#pragma unroll
        for (int off = 8; off; off >>= 1) den += __shfl_xor(den, off);
        float wn = ex / den;

        int base = (grp << 4) & 63;
        for (int e2 = 0; e2 < deg; e2 += 2) {
            int i1 = base + e2, i2 = base + e2 + 1;
            int s1 = __shfl(c, i1); float w1 = __shfl(wn, i1);
            int s2 = __shfl(c, i2); float w2 = __shfl(wn, i2);
            bool h2v = (e2 + 1) < deg;
            s2 = h2v ? s2 : s1;
            w2 = h2v ? w2 : 0.f;
            bf16x8 h1 = *reinterpret_cast<const bf16x8*>(hbase + ((size_t)(unsigned)s1 << 8) + foff);
            bf16x8 hh2 = *reinterpret_cast<const bf16x8*>(hbase + ((size_t)(unsigned)s2 << 8) + foff);
#pragma unroll
            for (int q = 0; q < 8; q++) acc[q] += w1 * (float)h1[q] + w2 * (float)hh2[q];
        }
    } else {
        float m = -1e30f;
        for (int i = beg + l; i < end; i += 16) {
            float t = alpha_s[col[i]] + ad;
            t = (t > 0.f) ? t : 0.2f * t;
            m = fmaxf(m, t);
        }
#pragma unroll
        for (int off = 8; off; off >>= 1) m = fmaxf(m, __shfl_xor(m, off));
        float den = 0.f;
        for (int i = beg + l; i < end; i += 16) {
            float t = alpha_s[col[i]] + ad;
            t = (t > 0.f) ? t : 0.2f * t;
            den += __expf(t - m);
        }
#pragma unroll
        for (int off = 8; off; off >>= 1) den += __shfl_xor(den, off);
        float rinv = 1.f / den;
        for (int e2 = beg; e2 < end; e2++) {
            int cc = col[e2];  // uniform within group
            float t = alpha_s[cc] + ad;
            t = (t > 0.f) ? t : 0.2f * t;
            float wv = __expf(t - m) * rinv;
            bf16x8 hv = *reinterpret_cast<const bf16x8*>(hbase + ((size_t)(unsigned)cc << 8) + foff);
#pragma unroll
            for (int q = 0; q < 8; q++) acc[q] += wv * (float)hv[q];
        }
    }

    // epilogue: lane l owns features l*8 .. l*8+7
    float4 b0 = *reinterpret_cast<const float4*>(bias + l * 8);
    float4 b1 = *reinterpret_cast<const float4*>(bias + l * 8 + 4);
    float bb[8] = {b0.x, b0.y, b0.z, b0.w, b1.x, b1.y, b1.z, b1.w};
    bf16x8 o;
#pragma unroll
    for (int q = 0; q < 8; q++) {
        float x = acc[q] + bb[q];
        x = (x > 0.f) ? x : __expf(x) - 1.f;
        o[q] = (__bf16)x;
    }
    *reinterpret_cast<bf16x8*>((char*)(outB + blockIdx.y * oS) + ((size_t)(unsigned)node << 8) + foff) = o;
}

// ================= fused MLP (relu GEMM -> GEMM) + segment pool =================

__global__ __launch_bounds__(256) void k_mlp_pool(const __bf16* __restrict__ AbB, size_t As_,
                                                  const __bf16* __restrict__ Wt1,
                                                  const __bf16* __restrict__ Wt2,
                                                  const float* __restrict__ b1,
                                                  const float* __restrict__ b2,
                                                  const int* __restrict__ bat0,
                                                  const int* __restrict__ bat1,
                                                  float* __restrict__ pB, size_t pS, int M) {
    __shared__ __align__(16) unsigned short As[64][136];
    __shared__ __align__(16) unsigned short Bs[128][136];
    const int tid = threadIdx.x;
    const int lane = tid & 63, w = tid >> 6;
    const int row0 = blockIdx.x * 64;
    const __bf16* Ab = AbB + blockIdx.y * As_;
    const int* batch = blockIdx.y ? bat1 : bat0;
    float* p = pB + blockIdx.y * pS;

#pragma unroll
    for (int t = 0; t < 4; t++) {
        int ch = t * 256 + tid;
        int r = ch >> 4, cx = ch & 15;
        int grow = row0 + r;
        bf16x8 v = {};
        if (grow < M) v = *reinterpret_cast<const bf16x8*>(Ab + (size_t)grow * 128 + cx * 8);
        *reinterpret_cast<bf16x8*>(&As[r][cx * 8]) = v;
    }
#pragma unroll
    for (int t = 0; t < 8; t++) {
        int ch = t * 256 + tid;
        int r = ch >> 4, cx = ch & 15;
        bf16x8 v = *reinterpret_cast<const bf16x8*>(Wt1 + (size_t)r * 128 + cx * 8);
        *reinterpret_cast<bf16x8*>(&Bs[r][cx * 8]) = v;
    }
    __syncthreads();

    {
        const int wr0 = (w >> 1) * 32;
        const int wc0 = (w & 1) * 64;
        f32x4 acc[2][4] = {};
#pragma unroll
        for (int ks = 0; ks < 4; ks++) {
            const int koff = ks * 32 + (lane >> 4) * 8;
            bf16x8 af[2], bfr[4];
#pragma unroll
            for (int mf = 0; mf < 2; mf++)
                af[mf] = *reinterpret_cast<const bf16x8*>(&As[wr0 + mf * 16 + (lane & 15)][koff]);
#pragma unroll
            for (int nf = 0; nf < 4; nf++)
                bfr[nf] = *reinterpret_cast<const bf16x8*>(&Bs[wc0 + nf * 16 + (lane & 15)][koff]);
#pragma unroll
            for (int mf = 0; mf < 2; mf++)
#pragma unroll
                for (int nf = 0; nf < 4; nf++)
                    acc[mf][nf] = __builtin_amdgcn_mfma_f32_16x16x32_bf16(af[mf], bfr[nf], acc[mf][nf], 0, 0, 0);
        }
        __syncthreads();
#pragma unroll
        for (int mf = 0; mf < 2; mf++)
#pragma unroll
            for (int r = 0; r < 4; r++) {
                int row = wr0 + mf * 16 + (lane >> 4) * 4 + r;
#pragma unroll
                for (int nf = 0; nf < 4; nf++) {
                    int colc = wc0 + nf * 16 + (lane & 15);
                    float v = fmaxf(acc[mf][nf][r] + b1[colc], 0.f);
                    As[row][colc] = __builtin_bit_cast(unsigned short, (__bf16)v);
                }
            }
#pragma unroll
        for (int t = 0; t < 4; t++) {
            int ch = t * 256 + tid;
            int r = ch >> 4, cx = ch & 15;
            bf16x8 v = *reinterpret_cast<const bf16x8*>(Wt2 + (size_t)r * 128 + cx * 8);
            *reinterpret_cast<bf16x8*>(&Bs[r][cx * 8]) = v;
        }
        __syncthreads();
    }

    const int wr2 = w * 16;
    f32x4 acc2[4] = {};
#pragma unroll
    for (int ks = 0; ks < 4; ks++) {
        const int koff = ks * 32 + (lane >> 4) * 8;
        bf16x8 a2 = *reinterpret_cast<const bf16x8*>(&As[wr2 + (lane & 15)][koff]);
#pragma unroll
        for (int nf = 0; nf < 4; nf++) {
            bf16x8 bf2 = *reinterpret_cast<const bf16x8*>(&Bs[nf * 16 + (lane & 15)][koff]);
            acc2[nf] = __builtin_amdgcn_mfma_f32_16x16x32_bf16(a2, bf2, acc2[nf], 0, 0, 0);
        }
    }

    int q = lane >> 4, c = lane & 15;
    bool full = (row0 + 63) < M;
    int g0 = batch[min(row0, M - 1)];
    int g1 = batch[min(row0 + 63, M - 1)];
    if (full && g0 == g1) {
        float s0 = acc2[0][0] + acc2[0][1] + acc2[0][2] + acc2[0][3];
        float s1 = acc2[1][0] + acc2[1][1] + acc2[1][2] + acc2[1][3];
        float s2 = acc2[2][0] + acc2[2][1] + acc2[2][2] + acc2[2][3];
        float s3 = acc2[3][0] + acc2[3][1] + acc2[3][2] + acc2[3][3];
        s0 += __shfl_xor(s0, 16); s0 += __shfl_xor(s0, 32);
        s1 += __shfl_xor(s1, 16); s1 += __shfl_xor(s1, 32);
        s2 += __shfl_xor(s2, 16); s2 += __shfl_xor(s2, 32);
        s3 += __shfl_xor(s3, 16); s3 += __shfl_xor(s3, 32);
        float v = (q & 2) ? ((q & 1) ? s3 : s2) : ((q & 1) ? s1 : s0);
        v += 16.f * b2[q * 16 + c];
        atomicAdd(&p[g0 * CDIM + q * 16 + c], v);
    } else {
        float b2v[4];
#pragma unroll
        for (int nf = 0; nf < 4; nf++) b2v[nf] = b2[nf * 16 + c];
#pragma unroll
        for (int r = 0; r < 4; r++) {
            int row = row0 + wr2 + q * 4 + r;
            if (row >= M) continue;
            int g = batch[row];
#pragma unroll
            for (int nf = 0; nf < 4; nf++)
                atomicAdd(&p[g * CDIM + nf * 16 + c], acc2[nf][r] + b2v[nf]);
        }
    }
}

// ================= final p1^T @ p2 =================

__global__ __launch_bounds__(64) void k_final(const float* __restrict__ p, float* __restrict__ out) {
    int i = blockIdx.x;
    int j = threadIdx.x;
    const float* p1 = p;
    const float* p2 = p + GDIM * CDIM;
    float s = 0.f;
    for (int g = 0; g < GDIM; ++g) s += p1[g * CDIM + i] * p2[g * CDIM + j];
    out[i * CDIM + j] = s;
}

// ================= host side =================

static inline size_t align_up(size_t x, size_t a) { return (x + a - 1) & ~(a - 1); }

struct Ws {
    __bf16 *Hb, *Yb;
    __bf16 *WtC, *Wt1, *Wt2;
    float *alpha_s, *alpha_d, *Wa, *p;
    int *row_ptr, *col;
    int *bcnt, *boff, *bcur;
    int2* part;
    size_t sNH, sN, sNp1, sE;
    size_t need;
};

static Ws carve(void* ws, bool combined) {
    char* p = (char*)ws;
    size_t off = 0;
    Ws w;
    int nb = combined ? 2 : 1;
    auto take = [&](size_t bytes) {
        char* r = p + off;
        off = align_up(off + bytes, 256);
        return r;
    };
    w.Hb = (__bf16*)take((size_t)nb * NNODES * HDIM * 2);
    w.Yb = (__bf16*)take((size_t)nb * NNODES * HDIM * 2);
    w.alpha_s = (float*)take((size_t)nb * NNODES * 4);
    w.alpha_d = (float*)take((size_t)nb * NNODES * 4);
    w.col = (int*)take((size_t)nb * NTOT * 4);
    w.part = (int2*)take((size_t)nb * NEDGES * 8);
    w.row_ptr = (int*)take((size_t)nb * (NNODES + 1) * 4);
    w.bcnt = (int*)take((size_t)2 * NB * 4);
    w.boff = (int*)take((size_t)2 * (NB + 1) * 4);
    w.bcur = (int*)take((size_t)2 * NB * 4);
    w.WtC = (__bf16*)take((size_t)2 * HDIM * HDIM * 2);
    w.Wt1 = (__bf16*)take((size_t)HDIM * HDIM * 2);
    w.Wt2 = (__bf16*)take((size_t)HDIM * CDIM * 2);
    w.Wa = (float*)take((size_t)512 * 4);
    w.p = (float*)take((size_t)2 * GDIM * CDIM * 4);
    w.need = off;
    size_t s = combined ? 1 : 0;
    w.sNH = s * (size_t)NNODES * HDIM;
    w.sN = s * (size_t)NNODES;
    w.sNp1 = s * (size_t)(NNODES + 1);
    w.sE = s * (size_t)NTOT;
    return w;
}

static void pipeline(const Ws& w, const float* xA, const float* xB,
                     const int* eiA, const int* eiB,
                     const int* batA, const int* batB,
                     const float* conv_b, const float* b1, const float* b2,
                     float* pbase, size_t pstride, int yc, hipStream_t stream) {
    const int N = NNODES, E = NEDGES;
    dim3 gC(NCHB, yc), gB(NB, yc), g1(1, yc);
    dim3 gW((N + 15) / 16, yc);
    dim3 gG((N + 63) / 64, yc);

    // ---- CSR build (bucketed, write-local) ----
    hipMemsetAsync(w.bcnt, 0, (size_t)yc * NB * 4, stream);
    k_bhist<<<gC, 256, 0, stream>>>(eiA, eiB, w.bcnt, E);
    k_bscan<<<g1, 256, 0, stream>>>(w.bcnt, w.boff, w.bcur);
    k_part<<<gC, 256, 0, stream>>>(eiA, eiB, w.bcur, w.part, E);
    k_place<<<gB, 256, 0, stream>>>(w.part, w.boff, w.row_ptr, w.sNp1, w.col, w.sE);

    // ---- conv layer 0 ----
    k_gemm_conv<true><<<gG, 256, 0, stream>>>(
        xA, xB, nullptr, 0, w.WtC, w.Wa, w.Wa + 128,
        w.alpha_s, w.alpha_d, w.sN, w.Hb, w.sNH, N);
    k_gat_agg<<<gW, 256, 0, stream>>>(w.Hb, w.sNH, w.alpha_s, w.alpha_d, w.sN,
                                      w.row_ptr, w.sNp1, w.col, w.sE, conv_b, w.Yb, w.sNH, N);
    // ---- conv layer 1 ----
    k_gemm_conv<false><<<gG, 256, 0, stream>>>(
        nullptr, nullptr, w.Yb, w.sNH, w.WtC + HDIM * HDIM, w.Wa + 256, w.Wa + 384,
        w.alpha_s, w.alpha_d, w.sN, w.Hb, w.sNH, N);
    k_gat_agg<<<gW, 256, 0, stream>>>(w.Hb, w.sNH, w.alpha_s, w.alpha_d, w.sN,
                                      w.row_ptr, w.sNp1, w.col, w.sE, conv_b + HDIM, w.Yb, w.sNH, N);
    // ---- fused MLP + pool ----
    k_mlp_pool<<<gG, 256, 0, stream>>>(w.Yb, w.sNH, w.Wt1, w.Wt2, b1, b2,
                                       batA, batB, pbase, pstride, N);
}

extern "C" void kernel_launch(void* const* d_in, const int* in_sizes, int n_in, void* d_out,
                              int out_size, void* d_ws, size_t ws_size, hipStream_t stream) {
    const float* x1      = (const float*)d_in[0];
    const float* x2      = (const float*)d_in[1];
    const float* convW   = (const float*)d_in[2];
    const float* att_src = (const float*)d_in[3];
    const float* att_dst = (const float*)d_in[4];
    const float* conv_b  = (const float*)d_in[5];
    const float* mlp_w1  = (const float*)d_in[6];
    const float* mlp_b1  = (const float*)d_in[7];
    const float* mlp_w2  = (const float*)d_in[8];
    const float* mlp_b2  = (const float*)d_in[9];
    const int* ei1       = (const int*)d_in[10];
    const int* batch1    = (const int*)d_in[11];
    const int* ei2       = (const int*)d_in[12];
    const int* batch2    = (const int*)d_in[13];
    float* out = (float*)d_out;

    Ws wc = carve(d_ws, true);
    bool combined = ws_size >= wc.need;
    Ws w = combined ? wc : carve(d_ws, false);

    k_setup<<<226, 256, 0, stream>>>(convW, mlp_w1, mlp_w2, att_src, att_dst,
                                     w.WtC, w.Wt1, w.Wt2, w.Wa, w.p);

    if (combined) {
        pipeline(w, x1, x2, ei1, ei2, batch1, batch2, conv_b,
                 mlp_b1, mlp_b2, w.p, (size_t)GDIM * CDIM, 2, stream);
    } else {
        pipeline(w, x1, x1, ei1, ei1, batch1, batch1, conv_b,
                 mlp_b1, mlp_b2, w.p, 0, 1, stream);
        pipeline(w, x2, x2, ei2, ei2, batch2, batch2, conv_b,
                 mlp_b1, mlp_b2, w.p + GDIM * CDIM, 0, 1, stream);
    }

    k_final<<<CDIM, 64, 0, stream>>>(w.p, out);
}